// Round 15
// baseline (1032.555 us; speedup 1.0000x reference)
//
#include <hip/hip_runtime.h>
#include <hip/hip_bf16.h>
#include <cmath>

namespace {

constexpr int kL      = 4;
constexpr int kDModel = 768;
constexpr int kDInner = 1536;
constexpr int kDtRank = 48;
constexpr int kDState = 16;
constexpr int kDConv  = 4;
constexpr int kSeq    = 1024;
constexpr int kPLd    = 96;    // proj row stride (80 used)
constexpr int kPB     = 128;   // x_proj weight rows padded for BN=128
constexpr int kVocab  = 32000;
constexpr int kCH     = 64;    // scan chunk length
constexpr int kNCH    = kSeq / kCH;  // 16 chunks
constexpr int kDN     = kDInner * kDState;  // 24576 (d,n) pairs
constexpr int kSplitIn  = 4;   // in_proj split-K parts
constexpr int kSplitOut = 8;   // out_proj split-K parts

// prep_kernel block ranges
constexpr int kPrepEmbed   = kSeq;                                   // 1024
constexpr int kPrepF2b     = kVocab * kDModel / (8 * 256);           // 12000
constexpr int kPrepDup2    = kL * kDModel * (kDInner / 4) / 256;     // 4608
constexpr int kPrepSplit3  = kL * 2 * kDInner * (kDModel / 4) / 256; // 9216
constexpr int kPrepSplit3x = kL * kPB * (kDInner / 4) / 256;         // 768
constexpr int kPrepBlocks  = kPrepEmbed + kPrepF2b + kPrepDup2 + kPrepSplit3 + kPrepSplit3x;

using short8 = __attribute__((ext_vector_type(8))) short;
using f32x4  = __attribute__((ext_vector_type(4))) float;

__device__ __forceinline__ float silu_f(float v) {
    return v / (1.f + __expf(-v));
}

__device__ __forceinline__ unsigned short f2bu(float v) {
    __hip_bfloat16 h = __float2bfloat16(v);
    return *reinterpret_cast<unsigned short*>(&h);
}

__device__ __forceinline__ void split_bf16(float v, __hip_bfloat16& hi, __hip_bfloat16& lo) {
    hi = __float2bfloat16(v);
    lo = __float2bfloat16(v - __bfloat162float(hi));
}

__device__ __forceinline__ void split_u(float v, unsigned short& hi, unsigned short& lo) {
    __hip_bfloat16 h, l;
    split_bf16(v, h, l);
    hi = *reinterpret_cast<unsigned short*>(&h);
    lo = *reinterpret_cast<unsigned short*>(&l);
}

// ------------- prep: embed+rms, emb f2b, out_proj dup2, in_proj split3,
// x_proj split3x — one launch, branch ladder on blockIdx.x
__global__ void __launch_bounds__(256) prep_kernel(
    const int* __restrict__ tokens, const float* __restrict__ embedding,
    const float* __restrict__ norm_w, const float* __restrict__ in_proj_w,
    const float* __restrict__ out_proj_w, const float* __restrict__ x_proj_w,
    float* __restrict__ x, __hip_bfloat16* __restrict__ h2,
    __hip_bfloat16* __restrict__ emb_bf, __hip_bfloat16* __restrict__ inw2,
    __hip_bfloat16* __restrict__ outw2, __hip_bfloat16* __restrict__ xw2) {
    const int tid = threadIdx.x;
    int b = blockIdx.x;

    if (b < kPrepEmbed) {
        // ---- embed + rmsnorm(norm_w[0]) -> x, h2 (3-term split) ----
        const int s = b;
        const int t = tokens[s];
        const float* src = embedding + (size_t)t * kDModel;
        float v[3];
        float ss = 0.f;
        #pragma unroll
        for (int j = 0; j < 3; ++j) {
            const int d = tid + j * 256;
            v[j] = src[d];
            x[(size_t)s * kDModel + d] = v[j];
            ss = fmaf(v[j], v[j], ss);
        }
        #pragma unroll
        for (int m = 32; m; m >>= 1) ss += __shfl_xor(ss, m);
        __shared__ float red[4];
        if ((tid & 63) == 0) red[tid >> 6] = ss;
        __syncthreads();
        const float total = red[0] + red[1] + red[2] + red[3];
        const float scale = rsqrtf(total / (float)kDModel + 1e-5f);
        __hip_bfloat16* dst = h2 + (size_t)s * 3 * kDModel;
        #pragma unroll
        for (int j = 0; j < 3; ++j) {
            const int d = tid + j * 256;
            const float hv = v[j] * scale * norm_w[d];
            __hip_bfloat16 hi, lo;
            split_bf16(hv, hi, lo);
            dst[d] = hi; dst[kDModel + d] = lo; dst[2 * kDModel + d] = hi;
        }
        return;
    }
    b -= kPrepEmbed;

    if (b < kPrepF2b) {
        // ---- embedding fp32 -> bf16, 8/thread ----
        const int i = (b * 256 + tid) * 8;
        const float4 a = *reinterpret_cast<const float4*>(embedding + i);
        const float4 c = *reinterpret_cast<const float4*>(embedding + i + 4);
        union { unsigned short u[8]; uint4 v; } pk;
        pk.u[0] = f2bu(a.x); pk.u[1] = f2bu(a.y); pk.u[2] = f2bu(a.z); pk.u[3] = f2bu(a.w);
        pk.u[4] = f2bu(c.x); pk.u[5] = f2bu(c.y); pk.u[6] = f2bu(c.z); pk.u[7] = f2bu(c.w);
        *reinterpret_cast<uint4*>(reinterpret_cast<unsigned short*>(emb_bf) + i) = pk.v;
        return;
    }
    b -= kPrepF2b;

    if (b < kPrepDup2) {
        // ---- out_proj: row = [hi | hi], 4-wide ----
        const int idx = b * 256 + tid;
        constexpr int cols = kDInner, c4cnt = kDInner / 4;
        const int r = idx / c4cnt, c = (idx % c4cnt) << 2;
        const float4 v = *reinterpret_cast<const float4*>(out_proj_w + (size_t)r * cols + c);
        ushort4 hi4 = {f2bu(v.x), f2bu(v.y), f2bu(v.z), f2bu(v.w)};
        unsigned short* row = reinterpret_cast<unsigned short*>(outw2) + (size_t)r * 2 * cols;
        *reinterpret_cast<ushort4*>(row + c) = hi4;
        *reinterpret_cast<ushort4*>(row + cols + c) = hi4;
        return;
    }
    b -= kPrepDup2;

    if (b < kPrepSplit3) {
        // ---- in_proj: row = [hi | hi | lo], 4-wide ----
        const int idx = b * 256 + tid;
        constexpr int cols = kDModel, c4cnt = kDModel / 4;
        const int r = idx / c4cnt, c = (idx % c4cnt) << 2;
        const float4 v = *reinterpret_cast<const float4*>(in_proj_w + (size_t)r * cols + c);
        ushort4 hi4, lo4;
        split_u(v.x, hi4.x, lo4.x); split_u(v.y, hi4.y, lo4.y);
        split_u(v.z, hi4.z, lo4.z); split_u(v.w, hi4.w, lo4.w);
        unsigned short* row = reinterpret_cast<unsigned short*>(inw2) + (size_t)r * 3 * cols;
        *reinterpret_cast<ushort4*>(row + c) = hi4;
        *reinterpret_cast<ushort4*>(row + cols + c) = hi4;
        *reinterpret_cast<ushort4*>(row + 2 * cols + c) = lo4;
        return;
    }
    b -= kPrepSplit3;

    {
        // ---- x_proj: 80 rows -> 128 padded, [hi | hi | lo], 4-wide ----
        const int idx = b * 256 + tid;
        constexpr int c4cnt = kDInner / 4;
        const int layer = idx / (kPB * c4cnt);
        const int rem   = idx % (kPB * c4cnt);
        const int r = rem / c4cnt, c = (rem % c4cnt) << 2;
        float4 v = {0.f, 0.f, 0.f, 0.f};
        if (r < kDtRank + 2 * kDState)
            v = *reinterpret_cast<const float4*>(
                x_proj_w + (size_t)layer * (kDtRank + 2 * kDState) * kDInner + (size_t)r * kDInner + c);
        ushort4 hi4, lo4;
        split_u(v.x, hi4.x, lo4.x); split_u(v.y, hi4.y, lo4.y);
        split_u(v.z, hi4.z, lo4.z); split_u(v.w, hi4.w, lo4.w);
        unsigned short* row = reinterpret_cast<unsigned short*>(xw2)
            + ((size_t)layer * kPB + r) * 3 * kDInner;
        *reinterpret_cast<ushort4*>(row + c) = hi4;
        *reinterpret_cast<ushort4*>(row + kDInner + c) = hi4;
        *reinterpret_cast<ushort4*>(row + 2 * kDInner + c) = lo4;
    }
}

// -- x += sum(kSplitOut out_proj partials); rmsnorm -> h2 (split) / h_bf
template <bool FINAL>
__global__ void __launch_bounds__(256) reduce_rms_kernel(
    const float* __restrict__ parts, size_t stride,
    const float* __restrict__ w, float* __restrict__ x,
    __hip_bfloat16* __restrict__ out) {
    const int s = blockIdx.x;
    float v[3];
    float ss = 0.f;
    #pragma unroll
    for (int j = 0; j < 3; ++j) {
        const int d = threadIdx.x + j * 256;
        const size_t off = (size_t)s * kDModel + d;
        float acc = x[off];
        #pragma unroll
        for (int p = 0; p < kSplitOut; ++p) acc += parts[(size_t)p * stride + off];
        v[j] = acc;
        x[off] = acc;
        ss = fmaf(acc, acc, ss);
    }
    #pragma unroll
    for (int m = 32; m; m >>= 1) ss += __shfl_xor(ss, m);
    __shared__ float red[4];
    if ((threadIdx.x & 63) == 0) red[threadIdx.x >> 6] = ss;
    __syncthreads();
    const float total = red[0] + red[1] + red[2] + red[3];
    const float scale = rsqrtf(total / (float)kDModel + 1e-5f);
    #pragma unroll
    for (int j = 0; j < 3; ++j) {
        const int d = threadIdx.x + j * 256;
        const float hv = v[j] * scale * w[d];
        if (FINAL) {
            out[(size_t)s * kDModel + d] = __float2bfloat16(hv);
        } else {
            __hip_bfloat16 hi, lo;
            split_bf16(hv, hi, lo);
            __hip_bfloat16* dst = out + (size_t)s * 3 * kDModel;
            dst[d] = hi; dst[kDModel + d] = lo; dst[2 * kDModel + d] = hi;
        }
    }
}

// ---------------------------------------------------------------- MFMA GEMM
// (layer GEMMs) 2-phase double-buffered 128x128 pipeline, round-7 config.
template <int BM, int BN, int KSPLIT>
__global__ void __launch_bounds__(256) mfma_gemm(
    const __hip_bfloat16* __restrict__ A, int lda,
    const __hip_bfloat16* __restrict__ B, int ldb,
    float* __restrict__ C, int ldc,
    int N, int K, size_t partStride) {
    constexpr int BK = 32;
    static_assert(BM == 128 && BN == 128, "staging assumes 128x128");
    __shared__ unsigned short As[2][BM * BK];
    __shared__ unsigned short Bs[2][BN * BK];
    const int tid  = threadIdx.x;
    const int lane = tid & 63;

    const int nwg = gridDim.x * gridDim.y;
    int bid = blockIdx.y * gridDim.x + blockIdx.x;
    {
        const int q = nwg >> 3, r = nwg & 7;
        const int xcd = bid & 7, pos = bid >> 3;
        bid = (xcd < r ? xcd * (q + 1) : r * (q + 1) + (xcd - r) * q) + pos;
    }
    const int m0 = (bid % gridDim.x) * BM;
    const int n0 = (bid / gridDim.x) * BN;

    const int Kp = K / KSPLIT;
    const int kbeg = (KSPLIT > 1) ? blockIdx.z * Kp : 0;
    float* Cw = (KSPLIT > 1) ? C + (size_t)blockIdx.z * partStride : C;
    constexpr int WM = BM / 2, WN = BN / 2;
    constexpr int MR = WM / 16, NR = WN / 16;
    const int wave = tid >> 6;
    const int wm = (wave >> 1) * WM, wn = (wave & 1) * WN;
    const int l15 = lane & 15, l4 = lane >> 4;
    f32x4 acc[MR][NR] = {};

    auto stage = [&](int buf, int k0) {
        #pragma unroll
        for (int i = 0; i < 2; ++i) {
            const int idx = tid + i * 256;
            const int r = idx >> 2, qv = idx & 3;
            const int qs = qv ^ ((r >> 1) & 3);
            __builtin_amdgcn_global_load_lds(
                (const __attribute__((address_space(1))) void*)(A + (size_t)(m0 + r) * lda + k0 + qs * 8),
                (__attribute__((address_space(3))) void*)(&As[buf][(idx - lane) * 8]),
                16, 0, 0);
        }
        #pragma unroll
        for (int i = 0; i < 2; ++i) {
            const int idx = tid + i * 256;
            const int r = idx >> 2, qv = idx & 3;
            const int qs = qv ^ ((r >> 1) & 3);
            __builtin_amdgcn_global_load_lds(
                (const __attribute__((address_space(1))) void*)(B + (size_t)(n0 + r) * ldb + k0 + qs * 8),
                (__attribute__((address_space(3))) void*)(&Bs[buf][(idx - lane) * 8]),
                16, 0, 0);
        }
    };

    const int nt = Kp / BK;
    int cur = 0;
    stage(0, kbeg);
    for (int t = 0; t < nt; ++t) {
        if (t + 1 < nt) {
            stage(cur ^ 1, kbeg + (t + 1) * BK);
            asm volatile("s_waitcnt vmcnt(4)" ::: "memory");
        } else {
            asm volatile("s_waitcnt vmcnt(0)" ::: "memory");
        }
        __builtin_amdgcn_s_barrier();

        short8 af[MR], bfv[NR];
        #pragma unroll
        for (int mi = 0; mi < MR; ++mi) {
            const int R = wm + mi * 16 + l15;
            af[mi] = *reinterpret_cast<const short8*>(&As[cur][(R * 4 + (l4 ^ ((R >> 1) & 3))) * 8]);
        }
        #pragma unroll
        for (int ni = 0; ni < NR; ++ni) {
            const int R = wn + ni * 16 + l15;
            bfv[ni] = *reinterpret_cast<const short8*>(&Bs[cur][(R * 4 + (l4 ^ ((R >> 1) & 3))) * 8]);
        }
        #pragma unroll
        for (int mi = 0; mi < MR; ++mi)
            #pragma unroll
            for (int ni = 0; ni < NR; ++ni)
                acc[mi][ni] = __builtin_amdgcn_mfma_f32_16x16x32_bf16(
                    af[mi], bfv[ni], acc[mi][ni], 0, 0, 0);

        asm volatile("s_waitcnt lgkmcnt(0)" ::: "memory");
        __builtin_amdgcn_s_barrier();
        cur ^= 1;
    }

    #pragma unroll
    for (int mi = 0; mi < MR; ++mi) {
        const int mrow = m0 + wm + mi * 16 + l4 * 4;
        #pragma unroll
        for (int ni = 0; ni < NR; ++ni) {
            const int ncol = n0 + wn + ni * 16 + l15;
            if (ncol >= N) continue;
            #pragma unroll
            for (int r = 0; r < 4; ++r)
                Cw[(size_t)(mrow + r) * ldc + ncol] = acc[mi][ni][r];
        }
    }
}

// --------------------- vocab GEMM: 512x256 tile, BK=32, 8 waves (4M x 2N),
// wave tile 128x128 (frag-reads/MFMA = 0.25), 3-buffer LDS (144 KB dynamic),
// counted vmcnt(6). stage(t+2) issued after tile-t barrier targets the
// buffer holding fully-consumed tile t-1 (race-free). Granule swizzle
// p ^= ((r>>1)&3) on stage-source and ds_read (2 lanes/bank).
__global__ void __launch_bounds__(512) vocab_gemm(
    const __hip_bfloat16* __restrict__ A,   // 1024 x 768
    const __hip_bfloat16* __restrict__ B,   // 32000 x 768
    float* __restrict__ C) {
    constexpr int BM = 512, BN = 256, BK = 32;
    constexpr int K = kDModel, NT = K / BK;          // 24
    constexpr int lda = kDModel, ldb = kDModel, ldc = kVocab;
    constexpr int ASZ = BM * BK;                     // 16384 shorts
    constexpr int BSZ = BN * BK;                     // 8192 shorts
    extern __shared__ unsigned short lds[];
    unsigned short* AsB = lds;                       // 3 x ASZ
    unsigned short* BsB = lds + 3 * ASZ;             // 3 x BSZ
    const int tid = threadIdx.x, lane = tid & 63;
    const int wave = tid >> 6;
    const int wr = wave >> 1;      // 0..3 (M quarter)
    const int wc = wave & 1;       // 0..1 (N half)
    const int l15 = lane & 15, l4 = lane >> 4;

    const int nwg = gridDim.x * gridDim.y;
    int bid = blockIdx.y * gridDim.x + blockIdx.x;
    {
        const int q = nwg >> 3, r = nwg & 7;
        const int xcd = bid & 7, pos = bid >> 3;
        bid = (xcd < r ? xcd * (q + 1) : r * (q + 1) + (xcd - r) * q) + pos;
    }
    const int m0 = (bid % gridDim.x) * BM;
    const int n0 = (bid / gridDim.x) * BN;

    f32x4 acc[8][8] = {};

    // stage one K-tile: A 2048 granules (4/thread), B 1024 (2/thread)
    auto stage = [&](int buf, int k0) {
        #pragma unroll
        for (int i = 0; i < 4; ++i) {
            const int idx = tid + i * 512;
            const int r = idx >> 2, p = idx & 3;
            const int ps = p ^ ((r >> 1) & 3);
            __builtin_amdgcn_global_load_lds(
                (const __attribute__((address_space(1))) void*)(A + (size_t)(m0 + r) * lda + k0 + ps * 8),
                (__attribute__((address_space(3))) void*)(AsB + (size_t)buf * ASZ + (size_t)(idx - lane) * 8),
                16, 0, 0);
        }
        #pragma unroll
        for (int i = 0; i < 2; ++i) {
            const int idx = tid + i * 512;
            const int r = idx >> 2, p = idx & 3;
            const int ps = p ^ ((r >> 1) & 3);
            __builtin_amdgcn_global_load_lds(
                (const __attribute__((address_space(1))) void*)(B + (size_t)(n0 + r) * ldb + k0 + ps * 8),
                (__attribute__((address_space(3))) void*)(BsB + (size_t)buf * BSZ + (size_t)(idx - lane) * 8),
                16, 0, 0);
        }
    };

    stage(0, 0);
    stage(1, BK);
    int cur = 0;
    for (int t = 0; t < NT; ++t) {
        if (t + 1 < NT) asm volatile("s_waitcnt vmcnt(6)" ::: "memory");
        else            asm volatile("s_waitcnt vmcnt(0)" ::: "memory");
        __builtin_amdgcn_s_barrier();
        if (t + 2 < NT) stage((t + 2) % 3, (t + 2) * BK);

        const unsigned short* Ab = AsB + (size_t)cur * ASZ;
        const unsigned short* Bb = BsB + (size_t)cur * BSZ;

        short8 af[8], bfv[8];
        #pragma unroll
        for (int mi = 0; mi < 8; ++mi) {
            const int R = wr * 128 + mi * 16 + l15;
            const int p = l4 ^ ((R >> 1) & 3);
            af[mi] = *reinterpret_cast<const short8*>(Ab + ((size_t)R * 4 + p) * 8);
        }
        #pragma unroll
        for (int ni = 0; ni < 8; ++ni) {
            const int R = wc * 128 + ni * 16 + l15;
            const int p = l4 ^ ((R >> 1) & 3);
            bfv[ni] = *reinterpret_cast<const short8*>(Bb + ((size_t)R * 4 + p) * 8);
        }
        __builtin_amdgcn_s_setprio(1);
        #pragma unroll
        for (int mi = 0; mi < 8; ++mi)
            #pragma unroll
            for (int ni = 0; ni < 8; ++ni)
                acc[mi][ni] = __builtin_amdgcn_mfma_f32_16x16x32_bf16(
                    af[mi], bfv[ni], acc[mi][ni], 0, 0, 0);
        __builtin_amdgcn_s_setprio(0);
        cur = (cur + 1) % 3;
    }

    // C/D layout: col = lane&15, row = (lane>>4)*4 + reg
    #pragma unroll
    for (int mg = 0; mg < 8; ++mg) {
        const int mrow = m0 + wr * 128 + mg * 16 + l4 * 4;
        #pragma unroll
        for (int ng = 0; ng < 8; ++ng) {
            const int ncol = n0 + wc * 128 + ng * 16 + l15;
            #pragma unroll
            for (int r = 0; r < 4; ++r)
                C[(size_t)(mrow + r) * ldc + ncol] = acc[mg][ng][r];
        }
    }
}

// ------------------------- reduce NP split-K partials: dst = sum(parts)
template <int NP>
__global__ void __launch_bounds__(256) reduce_parts(
    const float* __restrict__ parts, size_t stride,
    float* __restrict__ dst, int count) {
    const int i = (blockIdx.x * 256 + threadIdx.x) * 4;
    if (i >= count) return;
    float4 s = *reinterpret_cast<const float4*>(parts + i);
    #pragma unroll
    for (int p = 1; p < NP; ++p) {
        const float4 v = *reinterpret_cast<const float4*>(parts + (size_t)p * stride + i);
        s.x += v.x; s.y += v.y; s.z += v.z; s.w += v.w;
    }
    *reinterpret_cast<float4*>(dst + i) = s;
}

// -------- depthwise causal conv+silu, fused kSplitIn-part split-K reduce
__global__ void __launch_bounds__(256) conv_silu_kernel(
    const float* __restrict__ parts, size_t stride,
    const float* __restrict__ cw, const float* __restrict__ cb,
    float* __restrict__ xi, __hip_bfloat16* __restrict__ xi2) {
    const int s = blockIdx.x;
    const int d = blockIdx.y * 256 + threadIdx.x;
    float acc = cb[d];
    #pragma unroll
    for (int k = 0; k < kDConv; ++k) {
        const int sl = s - (kDConv - 1) + k;
        if (sl >= 0) {
            const size_t off = (size_t)sl * (2 * kDInner) + d;
            float xzv = parts[off];
            #pragma unroll
            for (int p = 1; p < kSplitIn; ++p) xzv += parts[(size_t)p * stride + off];
            acc = fmaf(xzv, cw[d * kDConv + k], acc);
        }
    }
    const float v = silu_f(acc);
    xi[(size_t)s * kDInner + d] = v;
    __hip_bfloat16 hi, lo;
    split_bf16(v, hi, lo);
    __hip_bfloat16* row = xi2 + (size_t)s * 3 * kDInner;
    row[d] = hi; row[kDInner + d] = lo; row[2 * kDInner + d] = hi;
}

// ------------------------------------------------- chunked selective scan
__device__ __forceinline__ void compute_dt_tile(
    const float* __restrict__ proj, const float* __restrict__ dtw,
    const float* __restrict__ dtb, int l0, int d0, int tid,
    float (*sP)[kDtRank], float (*sdtw)[kDtRank + 1], float (*sdt)[16]) {
    for (int idx = tid; idx < kCH * kDtRank; idx += 256) {
        const int r = idx / kDtRank, c = idx % kDtRank;
        sP[r][c] = proj[(size_t)(l0 + r) * kPLd + c];
    }
    for (int idx = tid; idx < 16 * kDtRank; idx += 256) {
        const int dd = idx / kDtRank, c = idx % kDtRank;
        sdtw[dd][c] = dtw[(size_t)(d0 + dd) * kDtRank + c];
    }
    __syncthreads();
    #pragma unroll
    for (int e = 0; e < 4; ++e) {
        const int idx = tid + e * 256;
        const int r = idx >> 4, dd = idx & 15;
        float acc = dtb[d0 + dd];
        #pragma unroll
        for (int k = 0; k < kDtRank; ++k)
            acc = fmaf(sP[r][k], sdtw[dd][k], acc);
        acc = (acc > 20.f) ? acc : log1pf(__expf(acc));  // softplus
        sdt[r][dd] = acc;
    }
}

__global__ void __launch_bounds__(256) scan_part1(
    const float* __restrict__ u, const float* __restrict__ proj,
    const float* __restrict__ A_log, const float* __restrict__ dtw,
    const float* __restrict__ dtb,
    float* __restrict__ P, float* __restrict__ S) {
    __shared__ float sP[kCH][kDtRank];
    __shared__ float sdtw[16][kDtRank + 1];
    __shared__ float sdt[kCH][16], su[kCH][16], sB[kCH][16];
    const int tid = threadIdx.x;
    const int n = tid & 15, dl = tid >> 4;
    const int d0 = blockIdx.x * 16;
    const int l0 = blockIdx.y * kCH;
    for (int idx = tid; idx < kCH * 16; idx += 256) {
        const int r = idx >> 4, c = idx & 15;
        su[r][c] = u[(size_t)(l0 + r) * kDInner + d0 + c];
        sB[r][c] = proj[(size_t)(l0 + r) * kPLd + kDtRank + c];
    }
    compute_dt_tile(proj, dtw, dtb, l0, d0, tid, sP, sdtw, sdt);
    __syncthreads();
    const int d = d0 + dl;
    const float Adn = -__expf(A_log[d * kDState + n]);
    float state = 0.f, sumA = 0.f;
    #pragma unroll 8
    for (int l = 0; l < kCH; ++l) {
        const float dtv = sdt[l][dl];
        const float adelta = __expf(dtv * Adn);
        const float mult = __expf(adelta);
        state = fmaf(state, mult, dtv * su[l][dl] * sB[l][n]);
        sumA += adelta;
    }
    const int dn = d * kDState + n;
    P[(size_t)blockIdx.y * kDN + dn] = __expf(sumA);
    S[(size_t)blockIdx.y * kDN + dn] = state;
}

__global__ void __launch_bounds__(256) scan_part2(
    const float* __restrict__ u, const float* __restrict__ proj,
    const float* __restrict__ A_log, const float* __restrict__ dtw,
    const float* __restrict__ dtb, const float* __restrict__ D_skip,
    const float* __restrict__ P, const float* __restrict__ S,
    const float* __restrict__ resparts, size_t rstride,
    __hip_bfloat16* __restrict__ g2) {
    __shared__ float sP[kCH][kDtRank];
    __shared__ float sdtw[16][kDtRank + 1];
    __shared__ float sdt[kCH][16], su[kCH][16], sB[kCH][16], sC[kCH][16];
    __shared__ float sy[kCH][16];
    const int tid = threadIdx.x;
    const int n = tid & 15, dl = tid >> 4;
    const int d0 = blockIdx.x * 16;
    const int l0 = blockIdx.y * kCH;
    for (int idx = tid; idx < kCH * 16; idx += 256) {
        const int r = idx >> 4, c = idx & 15;
        su[r][c] = u[(size_t)(l0 + r) * kDInner + d0 + c];
        sB[r][c] = proj[(size_t)(l0 + r) * kPLd + kDtRank + c];
        sC[r][c] = proj[(size_t)(l0 + r) * kPLd + kDtRank + kDState + c];
    }
    compute_dt_tile(proj, dtw, dtb, l0, d0, tid, sP, sdtw, sdt);
    const int dn = d0 * kDState + tid;
    float state = 0.f;
    for (int jj = 0; jj < (int)blockIdx.y; ++jj) {
        const size_t idx = (size_t)jj * kDN + dn;
        state = fmaf(state, P[idx], S[idx]);
    }
    __syncthreads();
    const int d = d0 + dl;
    const float Adn = -__expf(A_log[d * kDState + n]);
    const float Dv  = D_skip[d];
    for (int l = 0; l < kCH; ++l) {
        const float dtv = sdt[l][dl];
        const float uv  = su[l][dl];
        const float mult = __expf(__expf(dtv * Adn));
        state = fmaf(state, mult, dtv * uv * sB[l][n]);
        float contrib = state * sC[l][n];
        contrib += __shfl_xor(contrib, 8);
        contrib += __shfl_xor(contrib, 4);
        contrib += __shfl_xor(contrib, 2);
        contrib += __shfl_xor(contrib, 1);
        if (n == 0) sy[l][dl] = fmaf(uv, Dv, contrib);
    }
    __syncthreads();
    for (int idx = tid; idx < kCH * 16; idx += 256) {
        const int r = idx >> 4, c = idx & 15;
        const size_t roff = (size_t)(l0 + r) * (2 * kDInner) + kDInner + d0 + c;
        float res = resparts[roff];
        #pragma unroll
        for (int p = 1; p < kSplitIn; ++p) res += resparts[(size_t)p * rstride + roff];
        const float v = sy[r][c] * silu_f(res);
        __hip_bfloat16 hi, lo;
        split_bf16(v, hi, lo);
        __hip_bfloat16* row = g2 + (size_t)(l0 + r) * 2 * kDInner;
        row[d0 + c] = hi; row[kDInner + d0 + c] = lo;
    }
}

}  // namespace

extern "C" void kernel_launch(void* const* d_in, const int* in_sizes, int n_in,
                              void* d_out, int out_size, void* d_ws, size_t ws_size,
                              hipStream_t stream) {
    const int*   tokens       = (const int*)d_in[0];
    const float* embedding    = (const float*)d_in[1];
    const float* norm_w       = (const float*)d_in[2];
    const float* in_proj_w    = (const float*)d_in[3];
    const float* conv_w       = (const float*)d_in[4];
    const float* conv_b       = (const float*)d_in[5];
    const float* x_proj_w     = (const float*)d_in[6];
    const float* dt_proj_w    = (const float*)d_in[7];
    const float* dt_proj_b    = (const float*)d_in[8];
    const float* A_log        = (const float*)d_in[9];
    const float* D_skip       = (const float*)d_in[10];
    const float* out_proj_w   = (const float*)d_in[11];
    const float* final_norm_w = (const float*)d_in[12];
    float* out = (float*)d_out;

    constexpr int K3m = 3 * kDModel;   // 2304
    constexpr int K3i = 3 * kDInner;   // 4608
    constexpr int K2i = 2 * kDInner;   // 3072

    // 144 KB dynamic LDS for the vocab kernel (idempotent)
    (void)hipFuncSetAttribute((const void*)vocab_gemm,
                              hipFuncAttributeMaxDynamicSharedMemorySize, 147456);

    char* ws = (char*)d_ws;
    auto alloc = [&](size_t bytes) { char* p = ws; ws += (bytes + 255) & ~(size_t)255; return p; };
    float* x    = (float*)alloc((size_t)kSeq * kDModel * 4);
    float* xi   = (float*)alloc((size_t)kSeq * kDInner * 4);
    float* proj = (float*)alloc((size_t)kSeq * kPLd * 4);
    float* scanP  = (float*)alloc((size_t)kNCH * kDN * 4);
    float* scanS  = (float*)alloc((size_t)kNCH * kDN * 4);
    float* partsXZ = (float*)alloc((size_t)kSplitIn * kSeq * 2 * kDInner * 4);
    float* partsP  = (float*)alloc((size_t)24 * kSeq * kPLd * 4);
    float* partsO  = (float*)alloc((size_t)kSplitOut * kSeq * kDModel * 4);
    __hip_bfloat16* h_bf   = (__hip_bfloat16*)alloc((size_t)kSeq * kDModel * 2);
    __hip_bfloat16* h2     = (__hip_bfloat16*)alloc((size_t)kSeq * K3m * 2);
    __hip_bfloat16* xi2    = (__hip_bfloat16*)alloc((size_t)kSeq * K3i * 2);
    __hip_bfloat16* g2     = (__hip_bfloat16*)alloc((size_t)kSeq * K2i * 2);
    __hip_bfloat16* emb_bf = (__hip_bfloat16*)alloc((size_t)kVocab * kDModel * 2);
    __hip_bfloat16* inw2   = (__hip_bfloat16*)alloc((size_t)kL * 2 * kDInner * K3m * 2);
    __hip_bfloat16* outw2  = (__hip_bfloat16*)alloc((size_t)kL * kDModel * K2i * 2);
    __hip_bfloat16* xw2    = (__hip_bfloat16*)alloc((size_t)kL * kPB * K3i * 2);

    // one fused prep launch: embed+rms + all weight conversions
    prep_kernel<<<kPrepBlocks, 256, 0, stream>>>(
        tokens, embedding, norm_w, in_proj_w, out_proj_w, x_proj_w,
        x, h2, emb_bf, inw2, outw2, xw2);

    for (int i = 0; i < kL; ++i) {
        mfma_gemm<128, 128, kSplitIn><<<dim3(kSeq / 128, 2 * kDInner / 128, kSplitIn), 256, 0, stream>>>(
            h2, K3m, inw2 + (size_t)i * 2 * kDInner * K3m, K3m,
            partsXZ, 2 * kDInner, 2 * kDInner, K3m, (size_t)kSeq * 2 * kDInner);

        conv_silu_kernel<<<dim3(kSeq, kDInner / 256), 256, 0, stream>>>(
            partsXZ, (size_t)kSeq * 2 * kDInner,
            conv_w + (size_t)i * kDInner * kDConv, conv_b + (size_t)i * kDInner,
            xi, xi2);

        mfma_gemm<128, 128, 24><<<dim3(kSeq / 128, 1, 24), 256, 0, stream>>>(
            xi2, K3i, xw2 + (size_t)i * kPB * K3i, K3i,
            partsP, kPLd, kPLd, K3i, (size_t)kSeq * kPLd);
        reduce_parts<24><<<(kSeq * kPLd / 4 + 255) / 256, 256, 0, stream>>>(
            partsP, (size_t)kSeq * kPLd, proj, kSeq * kPLd);

        const float* A_l  = A_log + (size_t)i * kDInner * kDState;
        const float* dtw  = dt_proj_w + (size_t)i * kDInner * kDtRank;
        const float* dtb  = dt_proj_b + (size_t)i * kDInner;
        scan_part1<<<dim3(kDInner / 16, kNCH), 256, 0, stream>>>(
            xi, proj, A_l, dtw, dtb, scanP, scanS);
        scan_part2<<<dim3(kDInner / 16, kNCH), 256, 0, stream>>>(
            xi, proj, A_l, dtw, dtb, D_skip + (size_t)i * kDInner,
            scanP, scanS, partsXZ, (size_t)kSeq * 2 * kDInner, g2);

        mfma_gemm<128, 128, kSplitOut><<<dim3(kSeq / 128, kDModel / 128, kSplitOut), 256, 0, stream>>>(
            g2, K2i, outw2 + (size_t)i * kDModel * K2i, K2i,
            partsO, kDModel, kDModel, K2i, (size_t)kSeq * kDModel);

        if (i + 1 < kL) {
            reduce_rms_kernel<false><<<kSeq, 256, 0, stream>>>(
                partsO, (size_t)kSeq * kDModel, norm_w + (size_t)(i + 1) * kDModel, x, h2);
        } else {
            reduce_rms_kernel<true><<<kSeq, 256, 0, stream>>>(
                partsO, (size_t)kSeq * kDModel, final_norm_w, x, h_bf);
        }
    }

    // out = h_bf @ embedding^T  (1024 x 32000, K=768) — 512x256 deep pipeline
    vocab_gemm<<<dim3(kSeq / 512, kVocab / 256), 512, 147456, stream>>>(
        h_bf, emb_bf, out);
}

// Round 16
// 730.795 us; speedup vs baseline: 1.4129x; 1.4129x over previous
//
#include <hip/hip_runtime.h>
#include <hip/hip_bf16.h>
#include <cmath>

namespace {

constexpr int kL      = 4;
constexpr int kDModel = 768;
constexpr int kDInner = 1536;
constexpr int kDtRank = 48;
constexpr int kDState = 16;
constexpr int kDConv  = 4;
constexpr int kSeq    = 1024;
constexpr int kPLd    = 96;    // proj row stride (80 used)
constexpr int kPB     = 128;   // x_proj weight rows padded for BN=128
constexpr int kVocab  = 32000;
constexpr int kCH     = 64;    // scan chunk length
constexpr int kNCH    = kSeq / kCH;  // 16 chunks
constexpr int kDN     = kDInner * kDState;  // 24576 (d,n) pairs
constexpr int kSplitIn  = 4;   // in_proj split-K parts
constexpr int kSplitOut = 8;   // out_proj split-K parts

// prep_kernel block ranges
constexpr int kPrepEmbed   = kSeq;                                   // 1024
constexpr int kPrepF2b     = kVocab * kDModel / (8 * 256);           // 12000
constexpr int kPrepDup2    = kL * kDModel * (kDInner / 4) / 256;     // 4608
constexpr int kPrepSplit3  = kL * 2 * kDInner * (kDModel / 4) / 256; // 9216
constexpr int kPrepSplit3x = kL * kPB * (kDInner / 4) / 256;         // 768
constexpr int kPrepBlocks  = kPrepEmbed + kPrepF2b + kPrepDup2 + kPrepSplit3 + kPrepSplit3x;

using short8 = __attribute__((ext_vector_type(8))) short;
using f32x4  = __attribute__((ext_vector_type(4))) float;

__device__ __forceinline__ float silu_f(float v) {
    return v / (1.f + __expf(-v));
}

__device__ __forceinline__ unsigned short f2bu(float v) {
    __hip_bfloat16 h = __float2bfloat16(v);
    return *reinterpret_cast<unsigned short*>(&h);
}

__device__ __forceinline__ void split_bf16(float v, __hip_bfloat16& hi, __hip_bfloat16& lo) {
    hi = __float2bfloat16(v);
    lo = __float2bfloat16(v - __bfloat162float(hi));
}

__device__ __forceinline__ void split_u(float v, unsigned short& hi, unsigned short& lo) {
    __hip_bfloat16 h, l;
    split_bf16(v, h, l);
    hi = *reinterpret_cast<unsigned short*>(&h);
    lo = *reinterpret_cast<unsigned short*>(&l);
}

// ------------- prep: embed+rms, emb f2b, out_proj dup2, in_proj split3,
// x_proj split3x — one launch, branch ladder on blockIdx.x
__global__ void __launch_bounds__(256) prep_kernel(
    const int* __restrict__ tokens, const float* __restrict__ embedding,
    const float* __restrict__ norm_w, const float* __restrict__ in_proj_w,
    const float* __restrict__ out_proj_w, const float* __restrict__ x_proj_w,
    float* __restrict__ x, __hip_bfloat16* __restrict__ h2,
    __hip_bfloat16* __restrict__ emb_bf, __hip_bfloat16* __restrict__ inw2,
    __hip_bfloat16* __restrict__ outw2, __hip_bfloat16* __restrict__ xw2) {
    const int tid = threadIdx.x;
    int b = blockIdx.x;

    if (b < kPrepEmbed) {
        const int s = b;
        const int t = tokens[s];
        const float* src = embedding + (size_t)t * kDModel;
        float v[3];
        float ss = 0.f;
        #pragma unroll
        for (int j = 0; j < 3; ++j) {
            const int d = tid + j * 256;
            v[j] = src[d];
            x[(size_t)s * kDModel + d] = v[j];
            ss = fmaf(v[j], v[j], ss);
        }
        #pragma unroll
        for (int m = 32; m; m >>= 1) ss += __shfl_xor(ss, m);
        __shared__ float red[4];
        if ((tid & 63) == 0) red[tid >> 6] = ss;
        __syncthreads();
        const float total = red[0] + red[1] + red[2] + red[3];
        const float scale = rsqrtf(total / (float)kDModel + 1e-5f);
        __hip_bfloat16* dst = h2 + (size_t)s * 3 * kDModel;
        #pragma unroll
        for (int j = 0; j < 3; ++j) {
            const int d = tid + j * 256;
            const float hv = v[j] * scale * norm_w[d];
            __hip_bfloat16 hi, lo;
            split_bf16(hv, hi, lo);
            dst[d] = hi; dst[kDModel + d] = lo; dst[2 * kDModel + d] = hi;
        }
        return;
    }
    b -= kPrepEmbed;

    if (b < kPrepF2b) {
        const int i = (b * 256 + tid) * 8;
        const float4 a = *reinterpret_cast<const float4*>(embedding + i);
        const float4 c = *reinterpret_cast<const float4*>(embedding + i + 4);
        union { unsigned short u[8]; uint4 v; } pk;
        pk.u[0] = f2bu(a.x); pk.u[1] = f2bu(a.y); pk.u[2] = f2bu(a.z); pk.u[3] = f2bu(a.w);
        pk.u[4] = f2bu(c.x); pk.u[5] = f2bu(c.y); pk.u[6] = f2bu(c.z); pk.u[7] = f2bu(c.w);
        *reinterpret_cast<uint4*>(reinterpret_cast<unsigned short*>(emb_bf) + i) = pk.v;
        return;
    }
    b -= kPrepF2b;

    if (b < kPrepDup2) {
        const int idx = b * 256 + tid;
        constexpr int cols = kDInner, c4cnt = kDInner / 4;
        const int r = idx / c4cnt, c = (idx % c4cnt) << 2;
        const float4 v = *reinterpret_cast<const float4*>(out_proj_w + (size_t)r * cols + c);
        ushort4 hi4 = {f2bu(v.x), f2bu(v.y), f2bu(v.z), f2bu(v.w)};
        unsigned short* row = reinterpret_cast<unsigned short*>(outw2) + (size_t)r * 2 * cols;
        *reinterpret_cast<ushort4*>(row + c) = hi4;
        *reinterpret_cast<ushort4*>(row + cols + c) = hi4;
        return;
    }
    b -= kPrepDup2;

    if (b < kPrepSplit3) {
        const int idx = b * 256 + tid;
        constexpr int cols = kDModel, c4cnt = kDModel / 4;
        const int r = idx / c4cnt, c = (idx % c4cnt) << 2;
        const float4 v = *reinterpret_cast<const float4*>(in_proj_w + (size_t)r * cols + c);
        ushort4 hi4, lo4;
        split_u(v.x, hi4.x, lo4.x); split_u(v.y, hi4.y, lo4.y);
        split_u(v.z, hi4.z, lo4.z); split_u(v.w, hi4.w, lo4.w);
        unsigned short* row = reinterpret_cast<unsigned short*>(inw2) + (size_t)r * 3 * cols;
        *reinterpret_cast<ushort4*>(row + c) = hi4;
        *reinterpret_cast<ushort4*>(row + cols + c) = hi4;
        *reinterpret_cast<ushort4*>(row + 2 * cols + c) = lo4;
        return;
    }
    b -= kPrepSplit3;

    {
        const int idx = b * 256 + tid;
        constexpr int c4cnt = kDInner / 4;
        const int layer = idx / (kPB * c4cnt);
        const int rem   = idx % (kPB * c4cnt);
        const int r = rem / c4cnt, c = (rem % c4cnt) << 2;
        float4 v = {0.f, 0.f, 0.f, 0.f};
        if (r < kDtRank + 2 * kDState)
            v = *reinterpret_cast<const float4*>(
                x_proj_w + (size_t)layer * (kDtRank + 2 * kDState) * kDInner + (size_t)r * kDInner + c);
        ushort4 hi4, lo4;
        split_u(v.x, hi4.x, lo4.x); split_u(v.y, hi4.y, lo4.y);
        split_u(v.z, hi4.z, lo4.z); split_u(v.w, hi4.w, lo4.w);
        unsigned short* row = reinterpret_cast<unsigned short*>(xw2)
            + ((size_t)layer * kPB + r) * 3 * kDInner;
        *reinterpret_cast<ushort4*>(row + c) = hi4;
        *reinterpret_cast<ushort4*>(row + kDInner + c) = hi4;
        *reinterpret_cast<ushort4*>(row + 2 * kDInner + c) = lo4;
    }
}

// -- x += sum(kSplitOut out_proj partials); rmsnorm -> h2 (split) / h_bf
template <bool FINAL>
__global__ void __launch_bounds__(256) reduce_rms_kernel(
    const float* __restrict__ parts, size_t stride,
    const float* __restrict__ w, float* __restrict__ x,
    __hip_bfloat16* __restrict__ out) {
    const int s = blockIdx.x;
    float v[3];
    float ss = 0.f;
    #pragma unroll
    for (int j = 0; j < 3; ++j) {
        const int d = threadIdx.x + j * 256;
        const size_t off = (size_t)s * kDModel + d;
        float acc = x[off];
        #pragma unroll
        for (int p = 0; p < kSplitOut; ++p) acc += parts[(size_t)p * stride + off];
        v[j] = acc;
        x[off] = acc;
        ss = fmaf(acc, acc, ss);
    }
    #pragma unroll
    for (int m = 32; m; m >>= 1) ss += __shfl_xor(ss, m);
    __shared__ float red[4];
    if ((threadIdx.x & 63) == 0) red[threadIdx.x >> 6] = ss;
    __syncthreads();
    const float total = red[0] + red[1] + red[2] + red[3];
    const float scale = rsqrtf(total / (float)kDModel + 1e-5f);
    #pragma unroll
    for (int j = 0; j < 3; ++j) {
        const int d = threadIdx.x + j * 256;
        const float hv = v[j] * scale * w[d];
        if (FINAL) {
            out[(size_t)s * kDModel + d] = __float2bfloat16(hv);
        } else {
            __hip_bfloat16 hi, lo;
            split_bf16(hv, hi, lo);
            __hip_bfloat16* dst = out + (size_t)s * 3 * kDModel;
            dst[d] = hi; dst[kDModel + d] = lo; dst[2 * kDModel + d] = hi;
        }
    }
}

// ---------------------------------------------------------------- MFMA GEMM
// (layer GEMMs) 2-phase double-buffered 128x128 pipeline, round-7 config.
template <int BM, int BN, int KSPLIT>
__global__ void __launch_bounds__(256) mfma_gemm(
    const __hip_bfloat16* __restrict__ A, int lda,
    const __hip_bfloat16* __restrict__ B, int ldb,
    float* __restrict__ C, int ldc,
    int N, int K, size_t partStride) {
    constexpr int BK = 32;
    static_assert(BM == 128 && BN == 128, "staging assumes 128x128");
    __shared__ unsigned short As[2][BM * BK];
    __shared__ unsigned short Bs[2][BN * BK];
    const int tid  = threadIdx.x;
    const int lane = tid & 63;

    const int nwg = gridDim.x * gridDim.y;
    int bid = blockIdx.y * gridDim.x + blockIdx.x;
    {
        const int q = nwg >> 3, r = nwg & 7;
        const int xcd = bid & 7, pos = bid >> 3;
        bid = (xcd < r ? xcd * (q + 1) : r * (q + 1) + (xcd - r) * q) + pos;
    }
    const int m0 = (bid % gridDim.x) * BM;
    const int n0 = (bid / gridDim.x) * BN;

    const int Kp = K / KSPLIT;
    const int kbeg = (KSPLIT > 1) ? blockIdx.z * Kp : 0;
    float* Cw = (KSPLIT > 1) ? C + (size_t)blockIdx.z * partStride : C;
    constexpr int WM = BM / 2, WN = BN / 2;
    constexpr int MR = WM / 16, NR = WN / 16;
    const int wave = tid >> 6;
    const int wm = (wave >> 1) * WM, wn = (wave & 1) * WN;
    const int l15 = lane & 15, l4 = lane >> 4;
    f32x4 acc[MR][NR] = {};

    auto stage = [&](int buf, int k0) {
        #pragma unroll
        for (int i = 0; i < 2; ++i) {
            const int idx = tid + i * 256;
            const int r = idx >> 2, qv = idx & 3;
            const int qs = qv ^ ((r >> 1) & 3);
            __builtin_amdgcn_global_load_lds(
                (const __attribute__((address_space(1))) void*)(A + (size_t)(m0 + r) * lda + k0 + qs * 8),
                (__attribute__((address_space(3))) void*)(&As[buf][(idx - lane) * 8]),
                16, 0, 0);
        }
        #pragma unroll
        for (int i = 0; i < 2; ++i) {
            const int idx = tid + i * 256;
            const int r = idx >> 2, qv = idx & 3;
            const int qs = qv ^ ((r >> 1) & 3);
            __builtin_amdgcn_global_load_lds(
                (const __attribute__((address_space(1))) void*)(B + (size_t)(n0 + r) * ldb + k0 + qs * 8),
                (__attribute__((address_space(3))) void*)(&Bs[buf][(idx - lane) * 8]),
                16, 0, 0);
        }
    };

    const int nt = Kp / BK;
    int cur = 0;
    stage(0, kbeg);
    for (int t = 0; t < nt; ++t) {
        if (t + 1 < nt) {
            stage(cur ^ 1, kbeg + (t + 1) * BK);
            asm volatile("s_waitcnt vmcnt(4)" ::: "memory");
        } else {
            asm volatile("s_waitcnt vmcnt(0)" ::: "memory");
        }
        __builtin_amdgcn_s_barrier();

        short8 af[MR], bfv[NR];
        #pragma unroll
        for (int mi = 0; mi < MR; ++mi) {
            const int R = wm + mi * 16 + l15;
            af[mi] = *reinterpret_cast<const short8*>(&As[cur][(R * 4 + (l4 ^ ((R >> 1) & 3))) * 8]);
        }
        #pragma unroll
        for (int ni = 0; ni < NR; ++ni) {
            const int R = wn + ni * 16 + l15;
            bfv[ni] = *reinterpret_cast<const short8*>(&Bs[cur][(R * 4 + (l4 ^ ((R >> 1) & 3))) * 8]);
        }
        #pragma unroll
        for (int mi = 0; mi < MR; ++mi)
            #pragma unroll
            for (int ni = 0; ni < NR; ++ni)
                acc[mi][ni] = __builtin_amdgcn_mfma_f32_16x16x32_bf16(
                    af[mi], bfv[ni], acc[mi][ni], 0, 0, 0);

        asm volatile("s_waitcnt lgkmcnt(0)" ::: "memory");
        __builtin_amdgcn_s_barrier();
        cur ^= 1;
    }

    #pragma unroll
    for (int mi = 0; mi < MR; ++mi) {
        const int mrow = m0 + wm + mi * 16 + l4 * 4;
        #pragma unroll
        for (int ni = 0; ni < NR; ++ni) {
            const int ncol = n0 + wn + ni * 16 + l15;
            if (ncol >= N) continue;
            #pragma unroll
            for (int r = 0; r < 4; ++r)
                Cw[(size_t)(mrow + r) * ldc + ncol] = acc[mi][ni][r];
        }
    }
}

// ------------------------------- vocab GEMM: 256x256, BK=64, 8 waves, deep
// K-tile-granular double buffer (128 KB dynamic LDS) — round-14 verified.
__global__ void __launch_bounds__(512) vocab_gemm(
    const __hip_bfloat16* __restrict__ A,   // 1024 x 768
    const __hip_bfloat16* __restrict__ B,   // 32000 x 768
    float* __restrict__ C) {
    constexpr int BM = 256, BN = 256, BK = 64;
    constexpr int K = kDModel, NT = K / BK;      // 12
    constexpr int lda = kDModel, ldb = kDModel, ldc = kVocab;
    extern __shared__ unsigned short lds[];
    unsigned short* AsB = lds;                    // [2][BM*BK]
    unsigned short* BsB = lds + 2 * BM * BK;      // [2][BN*BK]
    const int tid = threadIdx.x, lane = tid & 63;
    const int wave = tid >> 6;
    const int wr = wave >> 2;      // 0..1 (M half)
    const int wc = wave & 3;       // 0..3 (N quarter)
    const int l15 = lane & 15, l4 = lane >> 4;

    const int nwg = gridDim.x * gridDim.y;
    int bid = blockIdx.y * gridDim.x + blockIdx.x;
    {
        const int q = nwg >> 3, r = nwg & 7;
        const int xcd = bid & 7, pos = bid >> 3;
        bid = (xcd < r ? xcd * (q + 1) : r * (q + 1) + (xcd - r) * q) + pos;
    }
    const int m0 = (bid % gridDim.x) * BM;
    const int n0 = (bid / gridDim.x) * BN;

    f32x4 acc[8][4] = {};

    auto stage = [&](int buf, int k0) {
        #pragma unroll
        for (int i = 0; i < 4; ++i) {
            const int idx = tid + i * 512;
            const int r = idx >> 3, p = idx & 7;
            const int ps = p ^ (r & 7);
            __builtin_amdgcn_global_load_lds(
                (const __attribute__((address_space(1))) void*)(A + (size_t)(m0 + r) * lda + k0 + ps * 8),
                (__attribute__((address_space(3))) void*)(AsB + (size_t)buf * BM * BK + (size_t)(idx - lane) * 8),
                16, 0, 0);
        }
        #pragma unroll
        for (int i = 0; i < 4; ++i) {
            const int idx = tid + i * 512;
            const int r = idx >> 3, p = idx & 7;
            const int ps = p ^ (r & 7);
            __builtin_amdgcn_global_load_lds(
                (const __attribute__((address_space(1))) void*)(B + (size_t)(n0 + r) * ldb + k0 + ps * 8),
                (__attribute__((address_space(3))) void*)(BsB + (size_t)buf * BN * BK + (size_t)(idx - lane) * 8),
                16, 0, 0);
        }
    };

    stage(0, 0);
    for (int t = 0; t < NT; ++t) {
        asm volatile("s_waitcnt vmcnt(0)" ::: "memory");
        __builtin_amdgcn_s_barrier();
        if (t + 1 < NT) stage((t + 1) & 1, (t + 1) * BK);
        const unsigned short* Ab = AsB + (size_t)(t & 1) * BM * BK;
        const unsigned short* Bb = BsB + (size_t)(t & 1) * BN * BK;

        short8 af[4][2], bfv[2][2];

#define LOAD_A(MQ)                                                          \
        _Pragma("unroll")                                                   \
        for (int mi = 0; mi < 4; ++mi) {                                    \
            _Pragma("unroll")                                               \
            for (int kk = 0; kk < 2; ++kk) {                                \
                const int R = wr * 128 + (MQ) * 64 + mi * 16 + l15;         \
                const int ps = (kk * 4 + l4) ^ (R & 7);                     \
                af[mi][kk] = *reinterpret_cast<const short8*>(              \
                    Ab + ((size_t)R * 8 + ps) * 8);                         \
            }                                                               \
        }
#define LOAD_B(NQ)                                                          \
        _Pragma("unroll")                                                   \
        for (int ni = 0; ni < 2; ++ni) {                                    \
            _Pragma("unroll")                                               \
            for (int kk = 0; kk < 2; ++kk) {                                \
                const int R = wc * 64 + (NQ) * 32 + ni * 16 + l15;          \
                const int ps = (kk * 4 + l4) ^ (R & 7);                     \
                bfv[ni][kk] = *reinterpret_cast<const short8*>(             \
                    Bb + ((size_t)R * 8 + ps) * 8);                         \
            }                                                               \
        }
#define QUAD(MQ, NQ)                                                        \
        __builtin_amdgcn_s_setprio(1);                                      \
        _Pragma("unroll")                                                   \
        for (int mi = 0; mi < 4; ++mi)                                      \
            _Pragma("unroll")                                               \
            for (int ni = 0; ni < 2; ++ni)                                  \
                _Pragma("unroll")                                           \
                for (int kk = 0; kk < 2; ++kk)                              \
                    acc[(MQ) * 4 + mi][(NQ) * 2 + ni] =                     \
                        __builtin_amdgcn_mfma_f32_16x16x32_bf16(            \
                            af[mi][kk], bfv[ni][kk],                        \
                            acc[(MQ) * 4 + mi][(NQ) * 2 + ni], 0, 0, 0);    \
        __builtin_amdgcn_s_setprio(0);

        LOAD_A(0); LOAD_B(0);
        QUAD(0, 0);
        LOAD_B(1);
        QUAD(0, 1);
        LOAD_A(1);
        QUAD(1, 1);
        LOAD_B(0);
        QUAD(1, 0);
#undef LOAD_A
#undef LOAD_B
#undef QUAD
    }

    // C/D layout: col = lane&15, row = (lane>>4)*4 + reg
    #pragma unroll
    for (int mg = 0; mg < 8; ++mg) {
        const int mrow = m0 + wr * 128 + mg * 16 + l4 * 4;
        #pragma unroll
        for (int ng = 0; ng < 4; ++ng) {
            const int ncol = n0 + wc * 64 + ng * 16 + l15;
            #pragma unroll
            for (int r = 0; r < 4; ++r)
                C[(size_t)(mrow + r) * ldc + ncol] = acc[mg][ng][r];
        }
    }
}

// ------------------------- reduce NP split-K partials: dst = sum(parts)
template <int NP>
__global__ void __launch_bounds__(256) reduce_parts(
    const float* __restrict__ parts, size_t stride,
    float* __restrict__ dst, int count) {
    const int i = (blockIdx.x * 256 + threadIdx.x) * 4;
    if (i >= count) return;
    float4 s = *reinterpret_cast<const float4*>(parts + i);
    #pragma unroll
    for (int p = 1; p < NP; ++p) {
        const float4 v = *reinterpret_cast<const float4*>(parts + (size_t)p * stride + i);
        s.x += v.x; s.y += v.y; s.z += v.z; s.w += v.w;
    }
    *reinterpret_cast<float4*>(dst + i) = s;
}

// -------- depthwise causal conv+silu, fused kSplitIn-part split-K reduce
__global__ void __launch_bounds__(256) conv_silu_kernel(
    const float* __restrict__ parts, size_t stride,
    const float* __restrict__ cw, const float* __restrict__ cb,
    float* __restrict__ xi, __hip_bfloat16* __restrict__ xi2) {
    const int s = blockIdx.x;
    const int d = blockIdx.y * 256 + threadIdx.x;
    float acc = cb[d];
    #pragma unroll
    for (int k = 0; k < kDConv; ++k) {
        const int sl = s - (kDConv - 1) + k;
        if (sl >= 0) {
            const size_t off = (size_t)sl * (2 * kDInner) + d;
            float xzv = parts[off];
            #pragma unroll
            for (int p = 1; p < kSplitIn; ++p) xzv += parts[(size_t)p * stride + off];
            acc = fmaf(xzv, cw[d * kDConv + k], acc);
        }
    }
    const float v = silu_f(acc);
    xi[(size_t)s * kDInner + d] = v;
    __hip_bfloat16 hi, lo;
    split_bf16(v, hi, lo);
    __hip_bfloat16* row = xi2 + (size_t)s * 3 * kDInner;
    row[d] = hi; row[kDInner + d] = lo; row[2 * kDInner + d] = hi;
}

// ------------------------------------------------- chunked selective scan
__device__ __forceinline__ void compute_dt_tile(
    const float* __restrict__ proj, const float* __restrict__ dtw,
    const float* __restrict__ dtb, int l0, int d0, int tid,
    float (*sP)[kDtRank], float (*sdtw)[kDtRank + 1], float (*sdt)[16]) {
    for (int idx = tid; idx < kCH * kDtRank; idx += 256) {
        const int r = idx / kDtRank, c = idx % kDtRank;
        sP[r][c] = proj[(size_t)(l0 + r) * kPLd + c];
    }
    for (int idx = tid; idx < 16 * kDtRank; idx += 256) {
        const int dd = idx / kDtRank, c = idx % kDtRank;
        sdtw[dd][c] = dtw[(size_t)(d0 + dd) * kDtRank + c];
    }
    __syncthreads();
    #pragma unroll
    for (int e = 0; e < 4; ++e) {
        const int idx = tid + e * 256;
        const int r = idx >> 4, dd = idx & 15;
        float acc = dtb[d0 + dd];
        #pragma unroll
        for (int k = 0; k < kDtRank; ++k)
            acc = fmaf(sP[r][k], sdtw[dd][k], acc);
        acc = (acc > 20.f) ? acc : log1pf(__expf(acc));  // softplus
        sdt[r][dd] = acc;
    }
}

__global__ void __launch_bounds__(256) scan_part1(
    const float* __restrict__ u, const float* __restrict__ proj,
    const float* __restrict__ A_log, const float* __restrict__ dtw,
    const float* __restrict__ dtb,
    float* __restrict__ P, float* __restrict__ S) {
    __shared__ float sP[kCH][kDtRank];
    __shared__ float sdtw[16][kDtRank + 1];
    __shared__ float sdt[kCH][16], su[kCH][16], sB[kCH][16];
    const int tid = threadIdx.x;
    const int n = tid & 15, dl = tid >> 4;
    const int d0 = blockIdx.x * 16;
    const int l0 = blockIdx.y * kCH;
    for (int idx = tid; idx < kCH * 16; idx += 256) {
        const int r = idx >> 4, c = idx & 15;
        su[r][c] = u[(size_t)(l0 + r) * kDInner + d0 + c];
        sB[r][c] = proj[(size_t)(l0 + r) * kPLd + kDtRank + c];
    }
    compute_dt_tile(proj, dtw, dtb, l0, d0, tid, sP, sdtw, sdt);
    __syncthreads();
    const int d = d0 + dl;
    const float Adn = -__expf(A_log[d * kDState + n]);
    float state = 0.f, sumA = 0.f;
    #pragma unroll 8
    for (int l = 0; l < kCH; ++l) {
        const float dtv = sdt[l][dl];
        const float adelta = __expf(dtv * Adn);
        const float mult = __expf(adelta);
        state = fmaf(state, mult, dtv * su[l][dl] * sB[l][n]);
        sumA += adelta;
    }
    const int dn = d * kDState + n;
    P[(size_t)blockIdx.y * kDN + dn] = __expf(sumA);
    S[(size_t)blockIdx.y * kDN + dn] = state;
}

__global__ void __launch_bounds__(256) scan_part2(
    const float* __restrict__ u, const float* __restrict__ proj,
    const float* __restrict__ A_log, const float* __restrict__ dtw,
    const float* __restrict__ dtb, const float* __restrict__ D_skip,
    const float* __restrict__ P, const float* __restrict__ S,
    const float* __restrict__ resparts, size_t rstride,
    __hip_bfloat16* __restrict__ g2) {
    __shared__ float sP[kCH][kDtRank];
    __shared__ float sdtw[16][kDtRank + 1];
    __shared__ float sdt[kCH][16], su[kCH][16], sB[kCH][16], sC[kCH][16];
    __shared__ float sy[kCH][16];
    const int tid = threadIdx.x;
    const int n = tid & 15, dl = tid >> 4;
    const int d0 = blockIdx.x * 16;
    const int l0 = blockIdx.y * kCH;
    for (int idx = tid; idx < kCH * 16; idx += 256) {
        const int r = idx >> 4, c = idx & 15;
        su[r][c] = u[(size_t)(l0 + r) * kDInner + d0 + c];
        sB[r][c] = proj[(size_t)(l0 + r) * kPLd + kDtRank + c];
        sC[r][c] = proj[(size_t)(l0 + r) * kPLd + kDtRank + kDState + c];
    }
    compute_dt_tile(proj, dtw, dtb, l0, d0, tid, sP, sdtw, sdt);
    const int dn = d0 * kDState + tid;
    float state = 0.f;
    for (int jj = 0; jj < (int)blockIdx.y; ++jj) {
        const size_t idx = (size_t)jj * kDN + dn;
        state = fmaf(state, P[idx], S[idx]);
    }
    __syncthreads();
    const int d = d0 + dl;
    const float Adn = -__expf(A_log[d * kDState + n]);
    const float Dv  = D_skip[d];
    for (int l = 0; l < kCH; ++l) {
        const float dtv = sdt[l][dl];
        const float uv  = su[l][dl];
        const float mult = __expf(__expf(dtv * Adn));
        state = fmaf(state, mult, dtv * uv * sB[l][n]);
        float contrib = state * sC[l][n];
        contrib += __shfl_xor(contrib, 8);
        contrib += __shfl_xor(contrib, 4);
        contrib += __shfl_xor(contrib, 2);
        contrib += __shfl_xor(contrib, 1);
        if (n == 0) sy[l][dl] = fmaf(uv, Dv, contrib);
    }
    __syncthreads();
    for (int idx = tid; idx < kCH * 16; idx += 256) {
        const int r = idx >> 4, c = idx & 15;
        const size_t roff = (size_t)(l0 + r) * (2 * kDInner) + kDInner + d0 + c;
        float res = resparts[roff];
        #pragma unroll
        for (int p = 1; p < kSplitIn; ++p) res += resparts[(size_t)p * rstride + roff];
        const float v = sy[r][c] * silu_f(res);
        __hip_bfloat16 hi, lo;
        split_bf16(v, hi, lo);
        __hip_bfloat16* row = g2 + (size_t)(l0 + r) * 2 * kDInner;
        row[d0 + c] = hi; row[kDInner + d0 + c] = lo;
    }
}

}  // namespace

extern "C" void kernel_launch(void* const* d_in, const int* in_sizes, int n_in,
                              void* d_out, int out_size, void* d_ws, size_t ws_size,
                              hipStream_t stream) {
    const int*   tokens       = (const int*)d_in[0];
    const float* embedding    = (const float*)d_in[1];
    const float* norm_w       = (const float*)d_in[2];
    const float* in_proj_w    = (const float*)d_in[3];
    const float* conv_w       = (const float*)d_in[4];
    const float* conv_b       = (const float*)d_in[5];
    const float* x_proj_w     = (const float*)d_in[6];
    const float* dt_proj_w    = (const float*)d_in[7];
    const float* dt_proj_b    = (const float*)d_in[8];
    const float* A_log        = (const float*)d_in[9];
    const float* D_skip       = (const float*)d_in[10];
    const float* out_proj_w   = (const float*)d_in[11];
    const float* final_norm_w = (const float*)d_in[12];
    float* out = (float*)d_out;

    constexpr int K3m = 3 * kDModel;   // 2304
    constexpr int K3i = 3 * kDInner;   // 4608
    constexpr int K2i = 2 * kDInner;   // 3072

    // 128 KB dynamic LDS for the vocab kernel (idempotent)
    (void)hipFuncSetAttribute((const void*)vocab_gemm,
                              hipFuncAttributeMaxDynamicSharedMemorySize, 131072);

    char* ws = (char*)d_ws;
    auto alloc = [&](size_t bytes) { char* p = ws; ws += (bytes + 255) & ~(size_t)255; return p; };
    float* x    = (float*)alloc((size_t)kSeq * kDModel * 4);
    float* xi   = (float*)alloc((size_t)kSeq * kDInner * 4);
    float* proj = (float*)alloc((size_t)kSeq * kPLd * 4);
    float* scanP  = (float*)alloc((size_t)kNCH * kDN * 4);
    float* scanS  = (float*)alloc((size_t)kNCH * kDN * 4);
    float* partsXZ = (float*)alloc((size_t)kSplitIn * kSeq * 2 * kDInner * 4);
    float* partsP  = (float*)alloc((size_t)24 * kSeq * kPLd * 4);
    float* partsO  = (float*)alloc((size_t)kSplitOut * kSeq * kDModel * 4);
    __hip_bfloat16* h_bf   = (__hip_bfloat16*)alloc((size_t)kSeq * kDModel * 2);
    __hip_bfloat16* h2     = (__hip_bfloat16*)alloc((size_t)kSeq * K3m * 2);
    __hip_bfloat16* xi2    = (__hip_bfloat16*)alloc((size_t)kSeq * K3i * 2);
    __hip_bfloat16* g2     = (__hip_bfloat16*)alloc((size_t)kSeq * K2i * 2);
    __hip_bfloat16* emb_bf = (__hip_bfloat16*)alloc((size_t)kVocab * kDModel * 2);
    __hip_bfloat16* inw2   = (__hip_bfloat16*)alloc((size_t)kL * 2 * kDInner * K3m * 2);
    __hip_bfloat16* outw2  = (__hip_bfloat16*)alloc((size_t)kL * kDModel * K2i * 2);
    __hip_bfloat16* xw2    = (__hip_bfloat16*)alloc((size_t)kL * kPB * K3i * 2);

    // one fused prep launch: embed+rms + all weight conversions
    prep_kernel<<<kPrepBlocks, 256, 0, stream>>>(
        tokens, embedding, norm_w, in_proj_w, out_proj_w, x_proj_w,
        x, h2, emb_bf, inw2, outw2, xw2);

    for (int i = 0; i < kL; ++i) {
        mfma_gemm<128, 128, kSplitIn><<<dim3(kSeq / 128, 2 * kDInner / 128, kSplitIn), 256, 0, stream>>>(
            h2, K3m, inw2 + (size_t)i * 2 * kDInner * K3m, K3m,
            partsXZ, 2 * kDInner, 2 * kDInner, K3m, (size_t)kSeq * 2 * kDInner);

        conv_silu_kernel<<<dim3(kSeq, kDInner / 256), 256, 0, stream>>>(
            partsXZ, (size_t)kSeq * 2 * kDInner,
            conv_w + (size_t)i * kDInner * kDConv, conv_b + (size_t)i * kDInner,
            xi, xi2);

        mfma_gemm<128, 128, 24><<<dim3(kSeq / 128, 1, 24), 256, 0, stream>>>(
            xi2, K3i, xw2 + (size_t)i * kPB * K3i, K3i,
            partsP, kPLd, kPLd, K3i, (size_t)kSeq * kPLd);
        reduce_parts<24><<<(kSeq * kPLd / 4 + 255) / 256, 256, 0, stream>>>(
            partsP, (size_t)kSeq * kPLd, proj, kSeq * kPLd);

        const float* A_l  = A_log + (size_t)i * kDInner * kDState;
        const float* dtw  = dt_proj_w + (size_t)i * kDInner * kDtRank;
        const float* dtb  = dt_proj_b + (size_t)i * kDInner;
        scan_part1<<<dim3(kDInner / 16, kNCH), 256, 0, stream>>>(
            xi, proj, A_l, dtw, dtb, scanP, scanS);
        scan_part2<<<dim3(kDInner / 16, kNCH), 256, 0, stream>>>(
            xi, proj, A_l, dtw, dtb, D_skip + (size_t)i * kDInner,
            scanP, scanS, partsXZ, (size_t)kSeq * 2 * kDInner, g2);

        mfma_gemm<128, 128, kSplitOut><<<dim3(kSeq / 128, kDModel / 128, kSplitOut), 256, 0, stream>>>(
            g2, K2i, outw2 + (size_t)i * kDModel * K2i, K2i,
            partsO, kDModel, kDModel, K2i, (size_t)kSeq * kDModel);

        if (i + 1 < kL) {
            reduce_rms_kernel<false><<<kSeq, 256, 0, stream>>>(
                partsO, (size_t)kSeq * kDModel, norm_w + (size_t)(i + 1) * kDModel, x, h2);
        } else {
            reduce_rms_kernel<true><<<kSeq, 256, 0, stream>>>(
                partsO, (size_t)kSeq * kDModel, final_norm_w, x, h_bf);
        }
    }

    // out = h_bf @ embedding^T   (1024 x 32000, K=768) — 256^2 deep pipeline
    vocab_gemm<<<dim3(kSeq / 256, kVocab / 256), 512, 131072, stream>>>(
        h_bf, emb_bf, out);
}

// Round 17
// 721.892 us; speedup vs baseline: 1.4303x; 1.0123x over previous
//
#include <hip/hip_runtime.h>
#include <hip/hip_bf16.h>
#include <cmath>

namespace {

constexpr int kL      = 4;
constexpr int kDModel = 768;
constexpr int kDInner = 1536;
constexpr int kDtRank = 48;
constexpr int kDState = 16;
constexpr int kDConv  = 4;
constexpr int kSeq    = 1024;
constexpr int kPLd    = 96;    // proj row stride (80 used)
constexpr int kPB     = 128;   // x_proj weight rows padded for BN=128
constexpr int kVocab  = 32000;
constexpr int kCH     = 64;    // scan chunk length
constexpr int kNCH    = kSeq / kCH;  // 16 chunks
constexpr int kDN     = kDInner * kDState;  // 24576 (d,n) pairs
constexpr int kSplitIn  = 4;   // in_proj split-K parts
constexpr int kSplitOut = 8;   // out_proj split-K parts
constexpr int kNoRemap  = 1 << 28;

// prep_kernel block ranges (8 elems/thread for converters)
constexpr int kPrepEmbed   = kSeq;                                   // 1024
constexpr int kPrepF2b     = kVocab * kDModel / (8 * 256);           // 12000
constexpr int kPrepOutW    = kL * kDModel * kDInner / (8 * 256);     // 2304
constexpr int kPrepInW     = kL * 2 * kDInner * kDModel / (8 * 256); // 4608
constexpr int kPrepXW      = kL * kPB * kDInner / (8 * 256);         // 384
constexpr int kPrepBlocks  = kPrepEmbed + kPrepF2b + kPrepOutW + kPrepInW + kPrepXW;

using short8 = __attribute__((ext_vector_type(8))) short;
using f32x4  = __attribute__((ext_vector_type(4))) float;

__device__ __forceinline__ float silu_f(float v) {
    return v / (1.f + __expf(-v));
}

__device__ __forceinline__ unsigned short f2bu(float v) {
    __hip_bfloat16 h = __float2bfloat16(v);
    return *reinterpret_cast<unsigned short*>(&h);
}

__device__ __forceinline__ void split_bf16(float v, __hip_bfloat16& hi, __hip_bfloat16& lo) {
    hi = __float2bfloat16(v);
    lo = __float2bfloat16(v - __bfloat162float(hi));
}

__device__ __forceinline__ void split_u(float v, unsigned short& hi, unsigned short& lo) {
    __hip_bfloat16 h, l;
    split_bf16(v, h, l);
    hi = *reinterpret_cast<unsigned short*>(&h);
    lo = *reinterpret_cast<unsigned short*>(&l);
}

// build 16B hi / lo packs from 8 consecutive floats
__device__ __forceinline__ void split8(const float* __restrict__ src,
                                       uint4& hiv, uint4& lov) {
    const float4 a = *reinterpret_cast<const float4*>(src);
    const float4 b = *reinterpret_cast<const float4*>(src + 4);
    union { unsigned short u[8]; uint4 v; } H, L;
    split_u(a.x, H.u[0], L.u[0]); split_u(a.y, H.u[1], L.u[1]);
    split_u(a.z, H.u[2], L.u[2]); split_u(a.w, H.u[3], L.u[3]);
    split_u(b.x, H.u[4], L.u[4]); split_u(b.y, H.u[5], L.u[5]);
    split_u(b.z, H.u[6], L.u[6]); split_u(b.w, H.u[7], L.u[7]);
    hiv = H.v; lov = L.v;
}

// ------------- prep: embed+rms, emb f2b, out_proj f2b, in_proj/x_proj split
// one launch, branch ladder on blockIdx.x. All split layouts are DEDUP'd:
// physical [hi | lo] (GEMM staging remaps conceptual K -> physical).
__global__ void __launch_bounds__(256) prep_kernel(
    const int* __restrict__ tokens, const float* __restrict__ embedding,
    const float* __restrict__ norm_w, const float* __restrict__ in_proj_w,
    const float* __restrict__ out_proj_w, const float* __restrict__ x_proj_w,
    float* __restrict__ x, __hip_bfloat16* __restrict__ h2,
    __hip_bfloat16* __restrict__ emb_bf, __hip_bfloat16* __restrict__ inw2,
    __hip_bfloat16* __restrict__ outw, __hip_bfloat16* __restrict__ xw2) {
    const int tid = threadIdx.x;
    int b = blockIdx.x;

    if (b < kPrepEmbed) {
        // ---- embed + rmsnorm(norm_w[0]) -> x, h2 (phys [hi|lo], stride 1536)
        const int s = b;
        const int t = tokens[s];
        const float* src = embedding + (size_t)t * kDModel;
        float v[3];
        float ss = 0.f;
        #pragma unroll
        for (int j = 0; j < 3; ++j) {
            const int d = tid + j * 256;
            v[j] = src[d];
            x[(size_t)s * kDModel + d] = v[j];
            ss = fmaf(v[j], v[j], ss);
        }
        #pragma unroll
        for (int m = 32; m; m >>= 1) ss += __shfl_xor(ss, m);
        __shared__ float red[4];
        if ((tid & 63) == 0) red[tid >> 6] = ss;
        __syncthreads();
        const float total = red[0] + red[1] + red[2] + red[3];
        const float scale = rsqrtf(total / (float)kDModel + 1e-5f);
        __hip_bfloat16* dst = h2 + (size_t)s * 2 * kDModel;
        #pragma unroll
        for (int j = 0; j < 3; ++j) {
            const int d = tid + j * 256;
            const float hv = v[j] * scale * norm_w[d];
            __hip_bfloat16 hi, lo;
            split_bf16(hv, hi, lo);
            dst[d] = hi; dst[kDModel + d] = lo;
        }
        return;
    }
    b -= kPrepEmbed;

    if (b < kPrepF2b) {
        // ---- embedding fp32 -> bf16, 8/thread, 16B store ----
        const int i = (b * 256 + tid) * 8;
        const float4 a = *reinterpret_cast<const float4*>(embedding + i);
        const float4 c = *reinterpret_cast<const float4*>(embedding + i + 4);
        union { unsigned short u[8]; uint4 v; } pk;
        pk.u[0] = f2bu(a.x); pk.u[1] = f2bu(a.y); pk.u[2] = f2bu(a.z); pk.u[3] = f2bu(a.w);
        pk.u[4] = f2bu(c.x); pk.u[5] = f2bu(c.y); pk.u[6] = f2bu(c.z); pk.u[7] = f2bu(c.w);
        *reinterpret_cast<uint4*>(reinterpret_cast<unsigned short*>(emb_bf) + i) = pk.v;
        return;
    }
    b -= kPrepF2b;

    if (b < kPrepOutW) {
        // ---- out_proj fp32 -> bf16 hi (plain, contiguous), 8/thread ----
        const int i = (b * 256 + tid) * 8;
        const float4 a = *reinterpret_cast<const float4*>(out_proj_w + i);
        const float4 c = *reinterpret_cast<const float4*>(out_proj_w + i + 4);
        union { unsigned short u[8]; uint4 v; } pk;
        pk.u[0] = f2bu(a.x); pk.u[1] = f2bu(a.y); pk.u[2] = f2bu(a.z); pk.u[3] = f2bu(a.w);
        pk.u[4] = f2bu(c.x); pk.u[5] = f2bu(c.y); pk.u[6] = f2bu(c.z); pk.u[7] = f2bu(c.w);
        *reinterpret_cast<uint4*>(reinterpret_cast<unsigned short*>(outw) + i) = pk.v;
        return;
    }
    b -= kPrepOutW;

    if (b < kPrepInW) {
        // ---- in_proj: phys row [hi | lo], stride 1536, 8/thread ----
        const int idx = b * 256 + tid;
        constexpr int cols = kDModel, c8 = kDModel / 8;   // 96
        const int r = idx / c8, c = (idx % c8) * 8;
        uint4 hiv, lov;
        split8(in_proj_w + (size_t)r * cols + c, hiv, lov);
        unsigned short* row = reinterpret_cast<unsigned short*>(inw2) + (size_t)r * 2 * cols;
        *reinterpret_cast<uint4*>(row + c) = hiv;
        *reinterpret_cast<uint4*>(row + cols + c) = lov;
        return;
    }
    b -= kPrepInW;

    {
        // ---- x_proj: 80 rows -> 128 padded, phys [hi | lo], stride 3072 ----
        const int idx = b * 256 + tid;
        constexpr int cols = kDInner, c8 = kDInner / 8;   // 192
        const int layer = idx / (kPB * c8);
        const int rem   = idx % (kPB * c8);
        const int r = rem / c8, c = (rem % c8) * 8;
        uint4 hiv = {0, 0, 0, 0}, lov = {0, 0, 0, 0};
        if (r < kDtRank + 2 * kDState)
            split8(x_proj_w + (size_t)layer * (kDtRank + 2 * kDState) * cols
                   + (size_t)r * cols + c, hiv, lov);
        unsigned short* row = reinterpret_cast<unsigned short*>(xw2)
            + ((size_t)layer * kPB + r) * 2 * cols;
        *reinterpret_cast<uint4*>(row + c) = hiv;
        *reinterpret_cast<uint4*>(row + cols + c) = lov;
    }
}

// -- x += sum(kSplitOut out_proj partials); rmsnorm -> h2 ([hi|lo]) / h_bf
template <bool FINAL>
__global__ void __launch_bounds__(256) reduce_rms_kernel(
    const float* __restrict__ parts, size_t stride,
    const float* __restrict__ w, float* __restrict__ x,
    __hip_bfloat16* __restrict__ out) {
    const int s = blockIdx.x;
    float v[3];
    float ss = 0.f;
    #pragma unroll
    for (int j = 0; j < 3; ++j) {
        const int d = threadIdx.x + j * 256;
        const size_t off = (size_t)s * kDModel + d;
        float acc = x[off];
        #pragma unroll
        for (int p = 0; p < kSplitOut; ++p) acc += parts[(size_t)p * stride + off];
        v[j] = acc;
        x[off] = acc;
        ss = fmaf(acc, acc, ss);
    }
    #pragma unroll
    for (int m = 32; m; m >>= 1) ss += __shfl_xor(ss, m);
    __shared__ float red[4];
    if ((threadIdx.x & 63) == 0) red[threadIdx.x >> 6] = ss;
    __syncthreads();
    const float total = red[0] + red[1] + red[2] + red[3];
    const float scale = rsqrtf(total / (float)kDModel + 1e-5f);
    #pragma unroll
    for (int j = 0; j < 3; ++j) {
        const int d = threadIdx.x + j * 256;
        const float hv = v[j] * scale * w[d];
        if (FINAL) {
            out[(size_t)s * kDModel + d] = __float2bfloat16(hv);
        } else {
            __hip_bfloat16 hi, lo;
            split_bf16(hv, hi, lo);
            __hip_bfloat16* dst = out + (size_t)s * 2 * kDModel;
            dst[d] = hi; dst[kDModel + d] = lo;
        }
    }
}

// ---------------------------------------------------------------- MFMA GEMM
// (layer GEMMs) 2-phase double-buffered 128x128 pipeline, round-7 config.
// TA/TB: conceptual->physical K remap (k' = k>=T ? k-T : k), implementing
// the dedup'd split layouts ([hi|lo|hi]->[hi|lo], [hi|hi|lo]->[hi|lo],
// [hi|hi]->[hi]). Segment boundaries are multiples of BK so no tile straddles.
template <int BM, int BN, int KSPLIT>
__global__ void __launch_bounds__(256) mfma_gemm(
    const __hip_bfloat16* __restrict__ A, int lda, int TA,
    const __hip_bfloat16* __restrict__ B, int ldb, int TB,
    float* __restrict__ C, int ldc,
    int N, int K, size_t partStride) {
    constexpr int BK = 32;
    static_assert(BM == 128 && BN == 128, "staging assumes 128x128");
    __shared__ unsigned short As[2][BM * BK];
    __shared__ unsigned short Bs[2][BN * BK];
    const int tid  = threadIdx.x;
    const int lane = tid & 63;

    const int nwg = gridDim.x * gridDim.y;
    int bid = blockIdx.y * gridDim.x + blockIdx.x;
    {
        const int q = nwg >> 3, r = nwg & 7;
        const int xcd = bid & 7, pos = bid >> 3;
        bid = (xcd < r ? xcd * (q + 1) : r * (q + 1) + (xcd - r) * q) + pos;
    }
    const int m0 = (bid % gridDim.x) * BM;
    const int n0 = (bid / gridDim.x) * BN;

    const int Kp = K / KSPLIT;
    const int kbeg = (KSPLIT > 1) ? blockIdx.z * Kp : 0;
    float* Cw = (KSPLIT > 1) ? C + (size_t)blockIdx.z * partStride : C;
    constexpr int WM = BM / 2, WN = BN / 2;
    constexpr int MR = WM / 16, NR = WN / 16;
    const int wave = tid >> 6;
    const int wm = (wave >> 1) * WM, wn = (wave & 1) * WN;
    const int l15 = lane & 15, l4 = lane >> 4;
    f32x4 acc[MR][NR] = {};

    auto stage = [&](int buf, int k0) {
        const int ka = (k0 >= TA) ? k0 - TA : k0;   // physical A offset
        const int kb = (k0 >= TB) ? k0 - TB : k0;   // physical B offset
        #pragma unroll
        for (int i = 0; i < 2; ++i) {
            const int idx = tid + i * 256;
            const int r = idx >> 2, qv = idx & 3;
            const int qs = qv ^ ((r >> 1) & 3);
            __builtin_amdgcn_global_load_lds(
                (const __attribute__((address_space(1))) void*)(A + (size_t)(m0 + r) * lda + ka + qs * 8),
                (__attribute__((address_space(3))) void*)(&As[buf][(idx - lane) * 8]),
                16, 0, 0);
        }
        #pragma unroll
        for (int i = 0; i < 2; ++i) {
            const int idx = tid + i * 256;
            const int r = idx >> 2, qv = idx & 3;
            const int qs = qv ^ ((r >> 1) & 3);
            __builtin_amdgcn_global_load_lds(
                (const __attribute__((address_space(1))) void*)(B + (size_t)(n0 + r) * ldb + kb + qs * 8),
                (__attribute__((address_space(3))) void*)(&Bs[buf][(idx - lane) * 8]),
                16, 0, 0);
        }
    };

    const int nt = Kp / BK;
    int cur = 0;
    stage(0, kbeg);
    for (int t = 0; t < nt; ++t) {
        if (t + 1 < nt) {
            stage(cur ^ 1, kbeg + (t + 1) * BK);
            asm volatile("s_waitcnt vmcnt(4)" ::: "memory");
        } else {
            asm volatile("s_waitcnt vmcnt(0)" ::: "memory");
        }
        __builtin_amdgcn_s_barrier();

        short8 af[MR], bfv[NR];
        #pragma unroll
        for (int mi = 0; mi < MR; ++mi) {
            const int R = wm + mi * 16 + l15;
            af[mi] = *reinterpret_cast<const short8*>(&As[cur][(R * 4 + (l4 ^ ((R >> 1) & 3))) * 8]);
        }
        #pragma unroll
        for (int ni = 0; ni < NR; ++ni) {
            const int R = wn + ni * 16 + l15;
            bfv[ni] = *reinterpret_cast<const short8*>(&Bs[cur][(R * 4 + (l4 ^ ((R >> 1) & 3))) * 8]);
        }
        #pragma unroll
        for (int mi = 0; mi < MR; ++mi)
            #pragma unroll
            for (int ni = 0; ni < NR; ++ni)
                acc[mi][ni] = __builtin_amdgcn_mfma_f32_16x16x32_bf16(
                    af[mi], bfv[ni], acc[mi][ni], 0, 0, 0);

        asm volatile("s_waitcnt lgkmcnt(0)" ::: "memory");
        __builtin_amdgcn_s_barrier();
        cur ^= 1;
    }

    #pragma unroll
    for (int mi = 0; mi < MR; ++mi) {
        const int mrow = m0 + wm + mi * 16 + l4 * 4;
        #pragma unroll
        for (int ni = 0; ni < NR; ++ni) {
            const int ncol = n0 + wn + ni * 16 + l15;
            if (ncol >= N) continue;
            #pragma unroll
            for (int r = 0; r < 4; ++r)
                Cw[(size_t)(mrow + r) * ldc + ncol] = acc[mi][ni][r];
        }
    }
}

// ------------------------------- vocab GEMM: 256x256, BK=64, 8 waves, deep
// K-tile-granular double buffer (128 KB dynamic LDS) — round-14 verified.
__global__ void __launch_bounds__(512) vocab_gemm(
    const __hip_bfloat16* __restrict__ A,   // 1024 x 768
    const __hip_bfloat16* __restrict__ B,   // 32000 x 768
    float* __restrict__ C) {
    constexpr int BM = 256, BN = 256, BK = 64;
    constexpr int K = kDModel, NT = K / BK;      // 12
    constexpr int lda = kDModel, ldb = kDModel, ldc = kVocab;
    extern __shared__ unsigned short lds[];
    unsigned short* AsB = lds;                    // [2][BM*BK]
    unsigned short* BsB = lds + 2 * BM * BK;      // [2][BN*BK]
    const int tid = threadIdx.x, lane = tid & 63;
    const int wave = tid >> 6;
    const int wr = wave >> 2;      // 0..1 (M half)
    const int wc = wave & 3;       // 0..3 (N quarter)
    const int l15 = lane & 15, l4 = lane >> 4;

    const int nwg = gridDim.x * gridDim.y;
    int bid = blockIdx.y * gridDim.x + blockIdx.x;
    {
        const int q = nwg >> 3, r = nwg & 7;
        const int xcd = bid & 7, pos = bid >> 3;
        bid = (xcd < r ? xcd * (q + 1) : r * (q + 1) + (xcd - r) * q) + pos;
    }
    const int m0 = (bid % gridDim.x) * BM;
    const int n0 = (bid / gridDim.x) * BN;

    f32x4 acc[8][4] = {};

    auto stage = [&](int buf, int k0) {
        #pragma unroll
        for (int i = 0; i < 4; ++i) {
            const int idx = tid + i * 512;
            const int r = idx >> 3, p = idx & 7;
            const int ps = p ^ (r & 7);
            __builtin_amdgcn_global_load_lds(
                (const __attribute__((address_space(1))) void*)(A + (size_t)(m0 + r) * lda + k0 + ps * 8),
                (__attribute__((address_space(3))) void*)(AsB + (size_t)buf * BM * BK + (size_t)(idx - lane) * 8),
                16, 0, 0);
        }
        #pragma unroll
        for (int i = 0; i < 4; ++i) {
            const int idx = tid + i * 512;
            const int r = idx >> 3, p = idx & 7;
            const int ps = p ^ (r & 7);
            __builtin_amdgcn_global_load_lds(
                (const __attribute__((address_space(1))) void*)(B + (size_t)(n0 + r) * ldb + k0 + ps * 8),
                (__attribute__((address_space(3))) void*)(BsB + (size_t)buf * BN * BK + (size_t)(idx - lane) * 8),
                16, 0, 0);
        }
    };

    stage(0, 0);
    for (int t = 0; t < NT; ++t) {
        asm volatile("s_waitcnt vmcnt(0)" ::: "memory");
        __builtin_amdgcn_s_barrier();
        if (t + 1 < NT) stage((t + 1) & 1, (t + 1) * BK);
        const unsigned short* Ab = AsB + (size_t)(t & 1) * BM * BK;
        const unsigned short* Bb = BsB + (size_t)(t & 1) * BN * BK;

        short8 af[4][2], bfv[2][2];

#define LOAD_A(MQ)                                                          \
        _Pragma("unroll")                                                   \
        for (int mi = 0; mi < 4; ++mi) {                                    \
            _Pragma("unroll")                                               \
            for (int kk = 0; kk < 2; ++kk) {                                \
                const int R = wr * 128 + (MQ) * 64 + mi * 16 + l15;         \
                const int ps = (kk * 4 + l4) ^ (R & 7);                     \
                af[mi][kk] = *reinterpret_cast<const short8*>(              \
                    Ab + ((size_t)R * 8 + ps) * 8);                         \
            }                                                               \
        }
#define LOAD_B(NQ)                                                          \
        _Pragma("unroll")                                                   \
        for (int ni = 0; ni < 2; ++ni) {                                    \
            _Pragma("unroll")                                               \
            for (int kk = 0; kk < 2; ++kk) {                                \
                const int R = wc * 64 + (NQ) * 32 + ni * 16 + l15;          \
                const int ps = (kk * 4 + l4) ^ (R & 7);                     \
                bfv[ni][kk] = *reinterpret_cast<const short8*>(             \
                    Bb + ((size_t)R * 8 + ps) * 8);                         \
            }                                                               \
        }
#define QUAD(MQ, NQ)                                                        \
        __builtin_amdgcn_s_setprio(1);                                      \
        _Pragma("unroll")                                                   \
        for (int mi = 0; mi < 4; ++mi)                                      \
            _Pragma("unroll")                                               \
            for (int ni = 0; ni < 2; ++ni)                                  \
                _Pragma("unroll")                                           \
                for (int kk = 0; kk < 2; ++kk)                              \
                    acc[(MQ) * 4 + mi][(NQ) * 2 + ni] =                     \
                        __builtin_amdgcn_mfma_f32_16x16x32_bf16(            \
                            af[mi][kk], bfv[ni][kk],                        \
                            acc[(MQ) * 4 + mi][(NQ) * 2 + ni], 0, 0, 0);    \
        __builtin_amdgcn_s_setprio(0);

        LOAD_A(0); LOAD_B(0);
        QUAD(0, 0);
        LOAD_B(1);
        QUAD(0, 1);
        LOAD_A(1);
        QUAD(1, 1);
        LOAD_B(0);
        QUAD(1, 0);
#undef LOAD_A
#undef LOAD_B
#undef QUAD
    }

    // C/D layout: col = lane&15, row = (lane>>4)*4 + reg
    #pragma unroll
    for (int mg = 0; mg < 8; ++mg) {
        const int mrow = m0 + wr * 128 + mg * 16 + l4 * 4;
        #pragma unroll
        for (int ng = 0; ng < 4; ++ng) {
            const int ncol = n0 + wc * 64 + ng * 16 + l15;
            #pragma unroll
            for (int r = 0; r < 4; ++r)
                C[(size_t)(mrow + r) * ldc + ncol] = acc[mg][ng][r];
        }
    }
}

// ------------------------- reduce NP split-K partials: dst = sum(parts)
template <int NP>
__global__ void __launch_bounds__(256) reduce_parts(
    const float* __restrict__ parts, size_t stride,
    float* __restrict__ dst, int count) {
    const int i = (blockIdx.x * 256 + threadIdx.x) * 4;
    if (i >= count) return;
    float4 s = *reinterpret_cast<const float4*>(parts + i);
    #pragma unroll
    for (int p = 1; p < NP; ++p) {
        const float4 v = *reinterpret_cast<const float4*>(parts + (size_t)p * stride + i);
        s.x += v.x; s.y += v.y; s.z += v.z; s.w += v.w;
    }
    *reinterpret_cast<float4*>(dst + i) = s;
}

// -------- depthwise causal conv+silu, fused kSplitIn-part split-K reduce
// xi2 written as phys [hi | lo], stride 3072
__global__ void __launch_bounds__(256) conv_silu_kernel(
    const float* __restrict__ parts, size_t stride,
    const float* __restrict__ cw, const float* __restrict__ cb,
    float* __restrict__ xi, __hip_bfloat16* __restrict__ xi2) {
    const int s = blockIdx.x;
    const int d = blockIdx.y * 256 + threadIdx.x;
    float acc = cb[d];
    #pragma unroll
    for (int k = 0; k < kDConv; ++k) {
        const int sl = s - (kDConv - 1) + k;
        if (sl >= 0) {
            const size_t off = (size_t)sl * (2 * kDInner) + d;
            float xzv = parts[off];
            #pragma unroll
            for (int p = 1; p < kSplitIn; ++p) xzv += parts[(size_t)p * stride + off];
            acc = fmaf(xzv, cw[d * kDConv + k], acc);
        }
    }
    const float v = silu_f(acc);
    xi[(size_t)s * kDInner + d] = v;
    __hip_bfloat16 hi, lo;
    split_bf16(v, hi, lo);
    __hip_bfloat16* row = xi2 + (size_t)s * 2 * kDInner;
    row[d] = hi; row[kDInner + d] = lo;
}

// ------------------------------------------------- chunked selective scan
__device__ __forceinline__ void compute_dt_tile(
    const float* __restrict__ proj, const float* __restrict__ dtw,
    const float* __restrict__ dtb, int l0, int d0, int tid,
    float (*sP)[kDtRank], float (*sdtw)[kDtRank + 1], float (*sdt)[16]) {
    for (int idx = tid; idx < kCH * kDtRank; idx += 256) {
        const int r = idx / kDtRank, c = idx % kDtRank;
        sP[r][c] = proj[(size_t)(l0 + r) * kPLd + c];
    }
    for (int idx = tid; idx < 16 * kDtRank; idx += 256) {
        const int dd = idx / kDtRank, c = idx % kDtRank;
        sdtw[dd][c] = dtw[(size_t)(d0 + dd) * kDtRank + c];
    }
    __syncthreads();
    #pragma unroll
    for (int e = 0; e < 4; ++e) {
        const int idx = tid + e * 256;
        const int r = idx >> 4, dd = idx & 15;
        float acc = dtb[d0 + dd];
        #pragma unroll
        for (int k = 0; k < kDtRank; ++k)
            acc = fmaf(sP[r][k], sdtw[dd][k], acc);
        acc = (acc > 20.f) ? acc : log1pf(__expf(acc));  // softplus
        sdt[r][dd] = acc;
    }
}

__global__ void __launch_bounds__(256) scan_part1(
    const float* __restrict__ u, const float* __restrict__ proj,
    const float* __restrict__ A_log, const float* __restrict__ dtw,
    const float* __restrict__ dtb,
    float* __restrict__ P, float* __restrict__ S) {
    __shared__ float sP[kCH][kDtRank];
    __shared__ float sdtw[16][kDtRank + 1];
    __shared__ float sdt[kCH][16], su[kCH][16], sB[kCH][16];
    const int tid = threadIdx.x;
    const int n = tid & 15, dl = tid >> 4;
    const int d0 = blockIdx.x * 16;
    const int l0 = blockIdx.y * kCH;
    for (int idx = tid; idx < kCH * 16; idx += 256) {
        const int r = idx >> 4, c = idx & 15;
        su[r][c] = u[(size_t)(l0 + r) * kDInner + d0 + c];
        sB[r][c] = proj[(size_t)(l0 + r) * kPLd + kDtRank + c];
    }
    compute_dt_tile(proj, dtw, dtb, l0, d0, tid, sP, sdtw, sdt);
    __syncthreads();
    const int d = d0 + dl;
    const float Adn = -__expf(A_log[d * kDState + n]);
    float state = 0.f, sumA = 0.f;
    #pragma unroll 8
    for (int l = 0; l < kCH; ++l) {
        const float dtv = sdt[l][dl];
        const float adelta = __expf(dtv * Adn);
        const float mult = __expf(adelta);
        state = fmaf(state, mult, dtv * su[l][dl] * sB[l][n]);
        sumA += adelta;
    }
    const int dn = d * kDState + n;
    P[(size_t)blockIdx.y * kDN + dn] = __expf(sumA);
    S[(size_t)blockIdx.y * kDN + dn] = state;
}

__global__ void __launch_bounds__(256) scan_part2(
    const float* __restrict__ u, const float* __restrict__ proj,
    const float* __restrict__ A_log, const float* __restrict__ dtw,
    const float* __restrict__ dtb, const float* __restrict__ D_skip,
    const float* __restrict__ P, const float* __restrict__ S,
    const float* __restrict__ resparts, size_t rstride,
    __hip_bfloat16* __restrict__ g2) {
    __shared__ float sP[kCH][kDtRank];
    __shared__ float sdtw[16][kDtRank + 1];
    __shared__ float sdt[kCH][16], su[kCH][16], sB[kCH][16], sC[kCH][16];
    __shared__ float sy[kCH][16];
    const int tid = threadIdx.x;
    const int n = tid & 15, dl = tid >> 4;
    const int d0 = blockIdx.x * 16;
    const int l0 = blockIdx.y * kCH;
    for (int idx = tid; idx < kCH * 16; idx += 256) {
        const int r = idx >> 4, c = idx & 15;
        su[r][c] = u[(size_t)(l0 + r) * kDInner + d0 + c];
        sB[r][c] = proj[(size_t)(l0 + r) * kPLd + kDtRank + c];
        sC[r][c] = proj[(size_t)(l0 + r) * kPLd + kDtRank + kDState + c];
    }
    compute_dt_tile(proj, dtw, dtb, l0, d0, tid, sP, sdtw, sdt);
    const int dn = d0 * kDState + tid;
    float state = 0.f;
    for (int jj = 0; jj < (int)blockIdx.y; ++jj) {
        const size_t idx = (size_t)jj * kDN + dn;
        state = fmaf(state, P[idx], S[idx]);
    }
    __syncthreads();
    const int d = d0 + dl;
    const float Adn = -__expf(A_log[d * kDState + n]);
    const float Dv  = D_skip[d];
    for (int l = 0; l < kCH; ++l) {
        const float dtv = sdt[l][dl];
        const float uv  = su[l][dl];
        const float mult = __expf(__expf(dtv * Adn));
        state = fmaf(state, mult, dtv * uv * sB[l][n]);
        float contrib = state * sC[l][n];
        contrib += __shfl_xor(contrib, 8);
        contrib += __shfl_xor(contrib, 4);
        contrib += __shfl_xor(contrib, 2);
        contrib += __shfl_xor(contrib, 1);
        if (n == 0) sy[l][dl] = fmaf(uv, Dv, contrib);
    }
    __syncthreads();
    for (int idx = tid; idx < kCH * 16; idx += 256) {
        const int r = idx >> 4, c = idx & 15;
        const size_t roff = (size_t)(l0 + r) * (2 * kDInner) + kDInner + d0 + c;
        float res = resparts[roff];
        #pragma unroll
        for (int p = 1; p < kSplitIn; ++p) res += resparts[(size_t)p * rstride + roff];
        const float v = sy[r][c] * silu_f(res);
        __hip_bfloat16 hi, lo;
        split_bf16(v, hi, lo);
        __hip_bfloat16* row = g2 + (size_t)(l0 + r) * 2 * kDInner;
        row[d0 + c] = hi; row[kDInner + d0 + c] = lo;
    }
}

}  // namespace

extern "C" void kernel_launch(void* const* d_in, const int* in_sizes, int n_in,
                              void* d_out, int out_size, void* d_ws, size_t ws_size,
                              hipStream_t stream) {
    const int*   tokens       = (const int*)d_in[0];
    const float* embedding    = (const float*)d_in[1];
    const float* norm_w       = (const float*)d_in[2];
    const float* in_proj_w    = (const float*)d_in[3];
    const float* conv_w       = (const float*)d_in[4];
    const float* conv_b       = (const float*)d_in[5];
    const float* x_proj_w     = (const float*)d_in[6];
    const float* dt_proj_w    = (const float*)d_in[7];
    const float* dt_proj_b    = (const float*)d_in[8];
    const float* A_log        = (const float*)d_in[9];
    const float* D_skip       = (const float*)d_in[10];
    const float* out_proj_w   = (const float*)d_in[11];
    const float* final_norm_w = (const float*)d_in[12];
    float* out = (float*)d_out;

    // conceptual K sizes (remapped to dedup'd physical layouts)
    constexpr int K3m = 3 * kDModel;   // 2304 (phys 1536)
    constexpr int K3i = 3 * kDInner;   // 4608 (phys 3072)
    constexpr int K2i = 2 * kDInner;   // 3072 (phys A 3072, phys B 1536)

    // 128 KB dynamic LDS for the vocab kernel (idempotent)
    (void)hipFuncSetAttribute((const void*)vocab_gemm,
                              hipFuncAttributeMaxDynamicSharedMemorySize, 131072);

    char* ws = (char*)d_ws;
    auto alloc = [&](size_t bytes) { char* p = ws; ws += (bytes + 255) & ~(size_t)255; return p; };
    float* x    = (float*)alloc((size_t)kSeq * kDModel * 4);
    float* xi   = (float*)alloc((size_t)kSeq * kDInner * 4);
    float* proj = (float*)alloc((size_t)kSeq * kPLd * 4);
    float* scanP  = (float*)alloc((size_t)kNCH * kDN * 4);
    float* scanS  = (float*)alloc((size_t)kNCH * kDN * 4);
    float* partsXZ = (float*)alloc((size_t)kSplitIn * kSeq * 2 * kDInner * 4);
    float* partsP  = (float*)alloc((size_t)24 * kSeq * kPLd * 4);
    float* partsO  = (float*)alloc((size_t)kSplitOut * kSeq * kDModel * 4);
    __hip_bfloat16* h_bf   = (__hip_bfloat16*)alloc((size_t)kSeq * kDModel * 2);
    __hip_bfloat16* h2     = (__hip_bfloat16*)alloc((size_t)kSeq * 2 * kDModel * 2);
    __hip_bfloat16* xi2    = (__hip_bfloat16*)alloc((size_t)kSeq * 2 * kDInner * 2);
    __hip_bfloat16* g2     = (__hip_bfloat16*)alloc((size_t)kSeq * 2 * kDInner * 2);
    __hip_bfloat16* emb_bf = (__hip_bfloat16*)alloc((size_t)kVocab * kDModel * 2);
    __hip_bfloat16* inw2   = (__hip_bfloat16*)alloc((size_t)kL * 2 * kDInner * 2 * kDModel * 2);
    __hip_bfloat16* outw   = (__hip_bfloat16*)alloc((size_t)kL * kDModel * kDInner * 2);
    __hip_bfloat16* xw2    = (__hip_bfloat16*)alloc((size_t)kL * kPB * 2 * kDInner * 2);

    // one fused prep launch: embed+rms + all weight conversions (dedup'd)
    prep_kernel<<<kPrepBlocks, 256, 0, stream>>>(
        tokens, embedding, norm_w, in_proj_w, out_proj_w, x_proj_w,
        x, h2, emb_bf, inw2, outw, xw2);

    for (int i = 0; i < kL; ++i) {
        // xz partials = h @ in_proj^T  (K=2304 conceptual; A thresh 1536, B 768)
        mfma_gemm<128, 128, kSplitIn><<<dim3(kSeq / 128, 2 * kDInner / 128, kSplitIn), 256, 0, stream>>>(
            h2, 2 * kDModel, 2 * kDModel,
            inw2 + (size_t)i * 2 * kDInner * 2 * kDModel, 2 * kDModel, kDModel,
            partsXZ, 2 * kDInner, 2 * kDInner, K3m, (size_t)kSeq * 2 * kDInner);

        conv_silu_kernel<<<dim3(kSeq, kDInner / 256), 256, 0, stream>>>(
            partsXZ, (size_t)kSeq * 2 * kDInner,
            conv_w + (size_t)i * kDInner * kDConv, conv_b + (size_t)i * kDInner,
            xi, xi2);

        // proj = xi @ x_proj^T  (K=4608 conceptual; A thresh 3072, B 1536)
        mfma_gemm<128, 128, 24><<<dim3(kSeq / 128, 1, 24), 256, 0, stream>>>(
            xi2, 2 * kDInner, 2 * kDInner,
            xw2 + (size_t)i * kPB * 2 * kDInner, 2 * kDInner, kDInner,
            partsP, kPLd, kPLd, K3i, (size_t)kSeq * kPLd);
        reduce_parts<24><<<(kSeq * kPLd / 4 + 255) / 256, 256, 0, stream>>>(
            partsP, (size_t)kSeq * kPLd, proj, kSeq * kPLd);

        const float* A_l  = A_log + (size_t)i * kDInner * kDState;
        const float* dtw  = dt_proj_w + (size_t)i * kDInner * kDtRank;
        const float* dtb  = dt_proj_b + (size_t)i * kDInner;
        scan_part1<<<dim3(kDInner / 16, kNCH), 256, 0, stream>>>(
            xi, proj, A_l, dtw, dtb, scanP, scanS);
        scan_part2<<<dim3(kDInner / 16, kNCH), 256, 0, stream>>>(
            xi, proj, A_l, dtw, dtb, D_skip + (size_t)i * kDInner,
            scanP, scanS, partsXZ, (size_t)kSeq * 2 * kDInner, g2);

        // out_proj partials = g @ W^T  (K=3072 conceptual; A no remap, B 1536)
        mfma_gemm<128, 128, kSplitOut><<<dim3(kSeq / 128, kDModel / 128, kSplitOut), 256, 0, stream>>>(
            g2, 2 * kDInner, kNoRemap,
            outw + (size_t)i * kDModel * kDInner, kDInner, kDInner,
            partsO, kDModel, kDModel, K2i, (size_t)kSeq * kDModel);

        if (i + 1 < kL) {
            reduce_rms_kernel<false><<<kSeq, 256, 0, stream>>>(
                partsO, (size_t)kSeq * kDModel, norm_w + (size_t)(i + 1) * kDModel, x, h2);
        } else {
            reduce_rms_kernel<true><<<kSeq, 256, 0, stream>>>(
                partsO, (size_t)kSeq * kDModel, final_norm_w, x, h_bf);
        }
    }

    // out = h_bf @ embedding^T   (1024 x 32000, K=768) — 256^2 deep pipeline
    vocab_gemm<<<dim3(kSeq / 256, kVocab / 256), 512, 131072, stream>>>(
        h_bf, emb_bf, out);
}